// Round 1
// baseline (1478.032 us; speedup 1.0000x reference)
//
#include <hip/hip_runtime.h>
#include <stdint.h>

// ---------------- problem constants ----------------
#define EDGES   300000
#define NLIT    50000
#define NGRAPH  4
#define EPG     75000          // edges per graph (contiguous)
#define HDIM    64

// ws layout (bytes)
#define OFF_HL2C   0
#define OFF_HC2L   38400000
#define OFF_AGG    76800000
#define OFF_WT     89600000
#define OFF_ROACC  (89600000 + 81920)

// weight-T element offsets within wT (bf16 elements)
#define WT_MSGL    0          // [3][64][64]
#define WT_MERGE0  12288      // [64][128]
#define WT_MERGER  20480      // [2][64][64]
#define WT_MSGC    28672      // [3][64][64]
#define WT_TOTAL   40960

typedef __attribute__((ext_vector_type(8))) short          s16x8;
typedef __attribute__((ext_vector_type(8))) unsigned short u16x8;
typedef __attribute__((ext_vector_type(4))) unsigned short u16x4;
typedef __attribute__((ext_vector_type(4))) float          f32x4;

__device__ __forceinline__ f32x4 mfma16(s16x8 a, s16x8 b, f32x4 c) {
    return __builtin_amdgcn_mfma_f32_16x16x32_bf16(a, b, c, 0, 0, 0);
}
__device__ __forceinline__ float bf2f(unsigned short s) {
    union { unsigned int u; float f; } v; v.u = ((unsigned int)s) << 16; return v.f;
}
__device__ __forceinline__ unsigned short f2bf(float f) {
    union { float f; unsigned int u; } v; v.f = f;
    return (unsigned short)((v.u + 0x7fffu + ((v.u >> 16) & 1u)) >> 16);
}

// one 64->64 layer: acc[rb][t] = bias + W^T @ bin   (D[f][e] orientation)
__device__ __forceinline__ void layer64(const unsigned short* __restrict__ wT,
                                        const float* __restrict__ bias,
                                        const s16x8 (&bin)[2][2],
                                        f32x4 (&acc)[2][4],
                                        int e16, int q)
{
#pragma unroll
    for (int t = 0; t < 4; ++t) {
        f32x4 bv = *(const f32x4*)(bias + 16 * t + 4 * q);
        acc[0][t] = bv; acc[1][t] = bv;
    }
#pragma unroll
    for (int t = 0; t < 4; ++t) {
#pragma unroll
        for (int kk = 0; kk < 2; ++kk) {
            s16x8 a = *(const s16x8*)(wT + (16 * t + e16) * 64 + kk * 32 + q * 8);
            acc[0][t] = mfma16(a, bin[0][kk], acc[0][t]);
            acc[1][t] = mfma16(a, bin[1][kk], acc[1][t]);
        }
    }
}

// C-layout acc -> B-fragments for next layer via swizzled per-wave LDS tile [32][64] bf16
template<bool RELU>
__device__ __forceinline__ void relayout(const f32x4 (&acc)[2][4], s16x8 (&out)[2][2],
                                         char* __restrict__ ldsw, int e16, int q)
{
#pragma unroll
    for (int rb = 0; rb < 2; ++rb) {
        int e = rb * 16 + e16;
        int rowoff = e * 128;
        int sw = (e & 7) << 4;
#pragma unroll
        for (int t = 0; t < 4; ++t) {
            f32x4 v = acc[rb][t];
            if (RELU) {
                v[0] = fmaxf(v[0], 0.f); v[1] = fmaxf(v[1], 0.f);
                v[2] = fmaxf(v[2], 0.f); v[3] = fmaxf(v[3], 0.f);
            }
            u16x4 p;
            p[0] = f2bf(v[0]); p[1] = f2bf(v[1]); p[2] = f2bf(v[2]); p[3] = f2bf(v[3]);
            *(u16x4*)(ldsw + rowoff + ((32 * t + 8 * q) ^ sw)) = p;
        }
    }
    asm volatile("s_waitcnt lgkmcnt(0)" ::: "memory");
    __builtin_amdgcn_sched_barrier(0);
#pragma unroll
    for (int rb = 0; rb < 2; ++rb) {
        int e = rb * 16 + e16;
        int rowoff = e * 128;
        int sw = (e & 7) << 4;
#pragma unroll
        for (int kk = 0; kk < 2; ++kk)
            out[rb][kk] = *(const s16x8*)(ldsw + rowoff + ((64 * kk + 16 * q) ^ sw));
    }
}

// -------- transpose + bf16-convert all round weights into ws --------
__global__ __launch_bounds__(256) void prep_weights(
    const float* __restrict__ msgl_W, const float* __restrict__ merge_W0,
    const float* __restrict__ merge_Wr, const float* __restrict__ msgc_W,
    unsigned short* __restrict__ wT)
{
    int gid = blockIdx.x * 256 + threadIdx.x;
    if (gid >= WT_TOTAL) return;
    float v;
    if (gid < WT_MERGE0) {                       // msglT [3][out][in]
        int m = gid >> 12, idx = gid & 4095, o = idx >> 6, i = idx & 63;
        v = msgl_W[(m << 12) + i * 64 + o];
    } else if (gid < WT_MERGER) {                // mergeW0T [64][128]
        int idx = gid - WT_MERGE0, o = idx >> 7, i = idx & 127;
        v = merge_W0[i * 64 + o];
    } else if (gid < WT_MSGC) {                  // mergeWrT [2][out][in]
        int idx = gid - WT_MERGER, m = idx >> 12, j = idx & 4095, o = j >> 6, i = j & 63;
        v = merge_Wr[(m << 12) + i * 64 + o];
    } else {                                     // msgcT [3][out][in]
        int idx = gid - WT_MSGC, m = idx >> 12, j = idx & 4095, o = j >> 6, i = j & 63;
        v = msgc_W[(m << 12) + i * 64 + o];
    }
    wT[gid] = f2bf(v);
}

// -------- init: h = feat @ W_init + b  (bf16), plus agg_l += h_c2l --------
__global__ __launch_bounds__(256) void init_kernel(
    const float* __restrict__ feat_l2c, const float* __restrict__ feat_c2l,
    const float* __restrict__ W_l2c, const float* __restrict__ b_l2c,
    const float* __restrict__ W_c2l, const float* __restrict__ b_c2l,
    unsigned short* __restrict__ h_l2c, unsigned short* __restrict__ h_c2l,
    float* __restrict__ agg, const int* __restrict__ lit_idx)
{
    int gid = blockIdx.x * 256 + threadIdx.x;
    if (gid >= EDGES * 8) return;
    int e = gid >> 3, fo = (gid & 7) << 3;
    float2 fl = *(const float2*)(feat_l2c + e * 2);
    float2 fc = *(const float2*)(feat_c2l + e * 2);

    u16x8 outl, outc;
    float vc[8];
#pragma unroll
    for (int j = 0; j < 8; ++j) {
        float wl0 = W_l2c[fo + j], wl1 = W_l2c[64 + fo + j];
        float wc0 = W_c2l[fo + j], wc1 = W_c2l[64 + fo + j];
        float vl = fl.x * wl0 + fl.y * wl1 + b_l2c[fo + j];
        vc[j] = fc.x * wc0 + fc.y * wc1 + b_c2l[fo + j];
        outl[j] = f2bf(vl);
        outc[j] = f2bf(vc[j]);
    }
    *(u16x8*)(h_l2c + e * 64 + fo) = outl;
    *(u16x8*)(h_c2l + e * 64 + fo) = outc;
    int lit = lit_idx[e];
#pragma unroll
    for (int j = 0; j < 8; ++j) atomicAdd(&agg[lit * 64 + fo + j], vc[j]);
}

// -------- literal update: x0=(agg[lit]-h_c2l)/8 -> MLP3 -> merge(., h_l2c) -> h_l2c --------
__global__ __launch_bounds__(192) void lit_update(
    const unsigned short* __restrict__ h_c2l,
    unsigned short* __restrict__ h_l2c,
    const float* __restrict__ agg,
    const int* __restrict__ lit_idx,
    const unsigned short* __restrict__ wT,
    const float* __restrict__ msgl_b,
    const float* __restrict__ merge_b0,
    const float* __restrict__ merge_br)
{
    __shared__ __align__(16) char lds[3 * 4096];
    int tid = threadIdx.x;
    int wv = tid >> 6, lane = tid & 63;
    int e16 = lane & 15, q = lane >> 4;
    char* ldsw = lds + wv * 4096;
    int base = blockIdx.x * 96 + wv * 32;
    int e_g[2] = { base + e16, base + 16 + e16 };
    int litn[2] = { lit_idx[e_g[0]], lit_idx[e_g[1]] };

    s16x8 bfrag[2][2];
#pragma unroll
    for (int rb = 0; rb < 2; ++rb) {
        int eg = e_g[rb], lit = litn[rb];
#pragma unroll
        for (int kk = 0; kk < 2; ++kk) {
            int f0 = kk * 32 + q * 8;
            const float* ap = agg + lit * 64 + f0;
            f32x4 a0 = *(const f32x4*)ap;
            f32x4 a1 = *(const f32x4*)(ap + 4);
            u16x8 hv = *(const u16x8*)(h_c2l + eg * 64 + f0);
            s16x8 b;
#pragma unroll
            for (int j = 0; j < 4; ++j) b[j]     = (short)f2bf((a0[j] - bf2f(hv[j]))     * 0.125f);
#pragma unroll
            for (int j = 0; j < 4; ++j) b[4 + j] = (short)f2bf((a1[j] - bf2f(hv[4 + j])) * 0.125f);
            bfrag[rb][kk] = b;
        }
    }

    f32x4 acc[2][4];
    layer64(wT + WT_MSGL,        msgl_b,       bfrag, acc, e16, q);
    relayout<true >(acc, bfrag, ldsw, e16, q);
    layer64(wT + WT_MSGL + 4096, msgl_b + 64,  bfrag, acc, e16, q);
    relayout<true >(acc, bfrag, ldsw, e16, q);
    layer64(wT + WT_MSGL + 8192, msgl_b + 128, bfrag, acc, e16, q);
    relayout<false>(acc, bfrag, ldsw, e16, q);        // m fragments

    // h_l2c fragments (read old value before overwrite)
    s16x8 hfrag[2][2];
#pragma unroll
    for (int rb = 0; rb < 2; ++rb)
#pragma unroll
        for (int kk = 0; kk < 2; ++kk)
            hfrag[rb][kk] = *(const s16x8*)(h_l2c + e_g[rb] * 64 + kk * 32 + q * 8);

    // merge layer 0: K=128, [m | h_l2c]
    const unsigned short* w0T = wT + WT_MERGE0;
#pragma unroll
    for (int t = 0; t < 4; ++t) {
        f32x4 bv = *(const f32x4*)(merge_b0 + 16 * t + 4 * q);
        acc[0][t] = bv; acc[1][t] = bv;
    }
#pragma unroll
    for (int t = 0; t < 4; ++t) {
#pragma unroll
        for (int kk = 0; kk < 4; ++kk) {
            s16x8 a = *(const s16x8*)(w0T + (16 * t + e16) * 128 + kk * 32 + q * 8);
            s16x8 b0 = (kk < 2) ? bfrag[0][kk] : hfrag[0][kk - 2];
            s16x8 b1 = (kk < 2) ? bfrag[1][kk] : hfrag[1][kk - 2];
            acc[0][t] = mfma16(a, b0, acc[0][t]);
            acc[1][t] = mfma16(a, b1, acc[1][t]);
        }
    }
    relayout<true>(acc, bfrag, ldsw, e16, q);
    layer64(wT + WT_MERGER,        merge_br,      bfrag, acc, e16, q);
    relayout<true>(acc, bfrag, ldsw, e16, q);
    layer64(wT + WT_MERGER + 4096, merge_br + 64, bfrag, acc, e16, q);

    // store new h_l2c (bf16)
#pragma unroll
    for (int rb = 0; rb < 2; ++rb) {
        int eg = e_g[rb];
#pragma unroll
        for (int t = 0; t < 4; ++t) {
            f32x4 v = acc[rb][t];
            u16x4 p;
            p[0] = f2bf(v[0]); p[1] = f2bf(v[1]); p[2] = f2bf(v[2]); p[3] = f2bf(v[3]);
            *(u16x4*)(h_l2c + eg * 64 + 16 * t + 4 * q) = p;
        }
    }
}

// -------- clause update: x0=(sum of 2 siblings)/8 -> MLP3 -> h_c2l (+agg_l atomics) --------
__global__ __launch_bounds__(192) void clause_update(
    const unsigned short* __restrict__ h_l2c,
    unsigned short* __restrict__ h_c2l,
    float* __restrict__ agg,
    const int* __restrict__ lit_idx,
    const unsigned short* __restrict__ msgcT,
    const float* __restrict__ msgc_b,
    int do_agg)
{
    __shared__ __align__(16) char lds[3 * 4096];
    int tid = threadIdx.x;
    int wv = tid >> 6, lane = tid & 63;
    int e16 = lane & 15, q = lane >> 4;
    char* ldsw = lds + wv * 4096;
    int base = blockIdx.x * 96 + wv * 32;
    int e_g[2] = { base + e16, base + 16 + e16 };

    s16x8 bfrag[2][2];
#pragma unroll
    for (int rb = 0; rb < 2; ++rb) {
        int eg = e_g[rb];
        int c3 = (eg / 3) * 3;
        int d = eg - c3;
        int e1 = c3 + (d == 0 ? 1 : 0);
        int e2 = c3 + (d == 2 ? 1 : 2);
#pragma unroll
        for (int kk = 0; kk < 2; ++kk) {
            int f0 = kk * 32 + q * 8;
            u16x8 h1 = *(const u16x8*)(h_l2c + e1 * 64 + f0);
            u16x8 h2 = *(const u16x8*)(h_l2c + e2 * 64 + f0);
            s16x8 b;
#pragma unroll
            for (int j = 0; j < 8; ++j)
                b[j] = (short)f2bf((bf2f(h1[j]) + bf2f(h2[j])) * 0.125f);
            bfrag[rb][kk] = b;
        }
    }

    f32x4 acc[2][4];
    layer64(msgcT,        msgc_b,       bfrag, acc, e16, q);
    relayout<true>(acc, bfrag, ldsw, e16, q);
    layer64(msgcT + 4096, msgc_b + 64,  bfrag, acc, e16, q);
    relayout<true>(acc, bfrag, ldsw, e16, q);
    layer64(msgcT + 8192, msgc_b + 128, bfrag, acc, e16, q);

#pragma unroll
    for (int rb = 0; rb < 2; ++rb) {
        int eg = e_g[rb];
        int lit = lit_idx[eg];
#pragma unroll
        for (int t = 0; t < 4; ++t) {
            f32x4 v = acc[rb][t];
            u16x4 p;
            p[0] = f2bf(v[0]); p[1] = f2bf(v[1]); p[2] = f2bf(v[2]); p[3] = f2bf(v[3]);
            *(u16x4*)(h_c2l + eg * 64 + 16 * t + 4 * q) = p;
            if (do_agg) {
#pragma unroll
                for (int r = 0; r < 4; ++r)
                    atomicAdd(&agg[lit * 64 + 16 * t + 4 * q + r], v[r]);
            }
        }
    }
}

// -------- readout stage 1: per-graph sum of h_c2l over contiguous 75000 edges --------
__global__ __launch_bounds__(256) void readout_sum(
    const unsigned short* __restrict__ h_c2l, float* __restrict__ ro_acc)
{
    __shared__ float lsum[32][64];
    int g = blockIdx.x >> 6, chunk = blockIdx.x & 63;
    int t = threadIdx.x;
    int fg = t & 7, el = t >> 3;
    float s[8] = {0, 0, 0, 0, 0, 0, 0, 0};
    for (int idx = chunk * 32 + el; idx < EPG; idx += 2048) {
        u16x8 hv = *(const u16x8*)(h_c2l + (g * EPG + idx) * 64 + fg * 8);
#pragma unroll
        for (int j = 0; j < 8; ++j) s[j] += bf2f(hv[j]);
    }
#pragma unroll
    for (int j = 0; j < 8; ++j) lsum[el][fg * 8 + j] = s[j];
    __syncthreads();
    if (t < 64) {
        float tot = 0.f;
#pragma unroll 8
        for (int r = 0; r < 32; ++r) tot += lsum[r][t];
        atomicAdd(&ro_acc[g * 64 + t], tot);
    }
}

// -------- readout stage 2: tiny MLP + sigmoid, one wave per graph --------
__global__ __launch_bounds__(256) void readout_mlp(
    const float* __restrict__ ro_acc, const float* __restrict__ ro_W,
    const float* __restrict__ ro_b, const float* __restrict__ ro_W2,
    const float* __restrict__ ro_b2, float* __restrict__ out)
{
    __shared__ float xb[NGRAPH][HDIM];
    __shared__ float yb[NGRAPH][HDIM];
    int g = threadIdx.x >> 6;
    int j = threadIdx.x & 63;
    xb[g][j] = ro_acc[g * HDIM + j] * (1.0f / 12500.0f);
    __syncthreads();
    float a = ro_b[j];
#pragma unroll 8
    for (int k = 0; k < HDIM; ++k) a += xb[g][k] * ro_W[k * HDIM + j];
    a = fmaxf(a, 0.0f);
    yb[g][j] = a;
    __syncthreads();
    float a2 = ro_b[HDIM + j];
#pragma unroll 8
    for (int k = 0; k < HDIM; ++k) a2 += yb[g][k] * ro_W[4096 + k * HDIM + j];
    a2 = fmaxf(a2, 0.0f);
    float p = a2 * ro_W2[j];
#pragma unroll
    for (int off = 32; off > 0; off >>= 1) p += __shfl_down(p, off, 64);
    if (j == 0) out[g] = 1.0f / (1.0f + expf(-(p + ro_b2[0])));
}

extern "C" void kernel_launch(void* const* d_in, const int* in_sizes, int n_in,
                              void* d_out, int out_size, void* d_ws, size_t ws_size,
                              hipStream_t stream)
{
    const float* feat_l2c = (const float*)d_in[0];
    const float* feat_c2l = (const float*)d_in[1];
    const int*   lit_idx  = (const int*)d_in[2];
    // d_in[3] (cls_idx) unused: edges are clause-major by construction
    const float* W_l2c    = (const float*)d_in[4];
    const float* b_l2c    = (const float*)d_in[5];
    const float* W_c2l    = (const float*)d_in[6];
    const float* b_c2l    = (const float*)d_in[7];
    const float* msgl_W   = (const float*)d_in[8];
    const float* msgl_b   = (const float*)d_in[9];
    const float* merge_W0 = (const float*)d_in[10];
    const float* merge_b0 = (const float*)d_in[11];
    const float* merge_Wr = (const float*)d_in[12];
    const float* merge_br = (const float*)d_in[13];
    const float* msgc_W   = (const float*)d_in[14];
    const float* msgc_b   = (const float*)d_in[15];
    const float* ro_W     = (const float*)d_in[16];
    const float* ro_b     = (const float*)d_in[17];
    const float* ro_W2    = (const float*)d_in[18];
    const float* ro_b2    = (const float*)d_in[19];

    char* ws = (char*)d_ws;
    unsigned short* h_l2c  = (unsigned short*)(ws + OFF_HL2C);
    unsigned short* h_c2l  = (unsigned short*)(ws + OFF_HC2L);
    float*          agg    = (float*)(ws + OFF_AGG);
    unsigned short* wT     = (unsigned short*)(ws + OFF_WT);
    float*          ro_acc = (float*)(ws + OFF_ROACC);

    hipMemsetAsync(agg, 0, NLIT * 64 * sizeof(float), stream);
    hipMemsetAsync(ro_acc, 0, NGRAPH * 64 * sizeof(float), stream);

    prep_weights<<<(WT_TOTAL + 255) / 256, 256, 0, stream>>>(msgl_W, merge_W0, merge_Wr, msgc_W, wT);
    init_kernel<<<EDGES * 8 / 256, 256, 0, stream>>>(feat_l2c, feat_c2l, W_l2c, b_l2c,
                                                     W_c2l, b_c2l, h_l2c, h_c2l, agg, lit_idx);
    for (int r = 0; r < 3; ++r) {
        lit_update<<<EDGES / 96, 192, 0, stream>>>(h_c2l, h_l2c, agg, lit_idx, wT,
                                                   msgl_b, merge_b0, merge_br);
        if (r < 2) hipMemsetAsync(agg, 0, NLIT * 64 * sizeof(float), stream);
        clause_update<<<EDGES / 96, 192, 0, stream>>>(h_l2c, h_c2l, agg, lit_idx,
                                                      wT + WT_MSGC, msgc_b, r < 2 ? 1 : 0);
    }
    readout_sum<<<256, 256, 0, stream>>>(h_c2l, ro_acc);
    readout_mlp<<<1, 256, 0, stream>>>(ro_acc, ro_W, ro_b, ro_W2, ro_b2, (float*)d_out);
}

// Round 2
// 669.113 us; speedup vs baseline: 2.2089x; 2.2089x over previous
//
#include <hip/hip_runtime.h>
#include <stdint.h>

// ---------------- problem constants ----------------
#define EDGES   300000
#define NLIT    50000
#define NGRAPH  4
#define EPG     75000          // edges per graph (contiguous)
#define HDIM    64

// ws layout (bytes)
#define OFF_HL2C   0
#define OFF_HC2L   38400000
#define OFF_AGG    76800000
#define OFF_WT     89600000
#define OFF_ROACC  89681920
#define OFF_CNT    89682944
#define OFF_CSROFF 89882944
#define OFF_CURSOR 90082948
#define OFF_EIDX   90282948
// end ~91.5 MB

// weight-T element offsets within wT (bf16 elements)
#define WT_MSGL    0          // [3][64][64]
#define WT_MERGE0  12288      // [64][128]
#define WT_MERGER  20480      // [2][64][64]
#define WT_MSGC    28672      // [3][64][64]
#define WT_TOTAL   40960

typedef __attribute__((ext_vector_type(8))) short          s16x8;
typedef __attribute__((ext_vector_type(8))) unsigned short u16x8;
typedef __attribute__((ext_vector_type(4))) unsigned short u16x4;
typedef __attribute__((ext_vector_type(4))) float          f32x4;

__device__ __forceinline__ f32x4 mfma16(s16x8 a, s16x8 b, f32x4 c) {
    return __builtin_amdgcn_mfma_f32_16x16x32_bf16(a, b, c, 0, 0, 0);
}
__device__ __forceinline__ float bf2f(unsigned short s) {
    union { unsigned int u; float f; } v; v.u = ((unsigned int)s) << 16; return v.f;
}
__device__ __forceinline__ unsigned short f2bf(float f) {
    union { float f; unsigned int u; } v; v.f = f;
    return (unsigned short)((v.u + 0x7fffu + ((v.u >> 16) & 1u)) >> 16);
}

// one 64->64 layer: acc[rb][t] = bias + W^T @ bin   (D[f][e] orientation)
__device__ __forceinline__ void layer64(const unsigned short* __restrict__ wT,
                                        const float* __restrict__ bias,
                                        const s16x8 (&bin)[2][2],
                                        f32x4 (&acc)[2][4],
                                        int e16, int q)
{
#pragma unroll
    for (int t = 0; t < 4; ++t) {
        f32x4 bv = *(const f32x4*)(bias + 16 * t + 4 * q);
        acc[0][t] = bv; acc[1][t] = bv;
    }
#pragma unroll
    for (int t = 0; t < 4; ++t) {
#pragma unroll
        for (int kk = 0; kk < 2; ++kk) {
            s16x8 a = *(const s16x8*)(wT + (16 * t + e16) * 64 + kk * 32 + q * 8);
            acc[0][t] = mfma16(a, bin[0][kk], acc[0][t]);
            acc[1][t] = mfma16(a, bin[1][kk], acc[1][t]);
        }
    }
}

// C-layout acc -> B-fragments for next layer via swizzled per-wave LDS tile [32][64] bf16
template<bool RELU>
__device__ __forceinline__ void relayout(const f32x4 (&acc)[2][4], s16x8 (&out)[2][2],
                                         char* __restrict__ ldsw, int e16, int q)
{
#pragma unroll
    for (int rb = 0; rb < 2; ++rb) {
        int e = rb * 16 + e16;
        int rowoff = e * 128;
        int sw = (e & 7) << 4;
#pragma unroll
        for (int t = 0; t < 4; ++t) {
            f32x4 v = acc[rb][t];
            if (RELU) {
                v[0] = fmaxf(v[0], 0.f); v[1] = fmaxf(v[1], 0.f);
                v[2] = fmaxf(v[2], 0.f); v[3] = fmaxf(v[3], 0.f);
            }
            u16x4 p;
            p[0] = f2bf(v[0]); p[1] = f2bf(v[1]); p[2] = f2bf(v[2]); p[3] = f2bf(v[3]);
            *(u16x4*)(ldsw + rowoff + ((32 * t + 8 * q) ^ sw)) = p;
        }
    }
    asm volatile("s_waitcnt lgkmcnt(0)" ::: "memory");
    __builtin_amdgcn_sched_barrier(0);
#pragma unroll
    for (int rb = 0; rb < 2; ++rb) {
        int e = rb * 16 + e16;
        int rowoff = e * 128;
        int sw = (e & 7) << 4;
#pragma unroll
        for (int kk = 0; kk < 2; ++kk)
            out[rb][kk] = *(const s16x8*)(ldsw + rowoff + ((64 * kk + 16 * q) ^ sw));
    }
}

// -------- transpose + bf16-convert all round weights into ws --------
__global__ __launch_bounds__(256) void prep_weights(
    const float* __restrict__ msgl_W, const float* __restrict__ merge_W0,
    const float* __restrict__ merge_Wr, const float* __restrict__ msgc_W,
    unsigned short* __restrict__ wT)
{
    int gid = blockIdx.x * 256 + threadIdx.x;
    if (gid >= WT_TOTAL) return;
    float v;
    if (gid < WT_MERGE0) {                       // msglT [3][out][in]
        int m = gid >> 12, idx = gid & 4095, o = idx >> 6, i = idx & 63;
        v = msgl_W[(m << 12) + i * 64 + o];
    } else if (gid < WT_MERGER) {                // mergeW0T [64][128]
        int idx = gid - WT_MERGE0, o = idx >> 7, i = idx & 127;
        v = merge_W0[i * 64 + o];
    } else if (gid < WT_MSGC) {                  // mergeWrT [2][out][in]
        int idx = gid - WT_MERGER, m = idx >> 12, j = idx & 4095, o = j >> 6, i = j & 63;
        v = merge_Wr[(m << 12) + i * 64 + o];
    } else {                                     // msgcT [3][out][in]
        int idx = gid - WT_MSGC, m = idx >> 12, j = idx & 4095, o = j >> 6, i = j & 63;
        v = msgc_W[(m << 12) + i * 64 + o];
    }
    wT[gid] = f2bf(v);
}

// -------- CSR build: histogram -> scan -> scatter --------
__global__ __launch_bounds__(256) void csr_hist(const int* __restrict__ lit_idx,
                                                int* __restrict__ cnt)
{
    int e = blockIdx.x * 256 + threadIdx.x;
    if (e < EDGES) atomicAdd(&cnt[lit_idx[e]], 1);
}

#define SCAN_T 1024
__global__ __launch_bounds__(SCAN_T) void csr_scan(const int* __restrict__ cnt,
                                                   int* __restrict__ off,
                                                   int* __restrict__ cursor)
{
    __shared__ int part[SCAN_T];
    int t = threadIdx.x;
    const int chunk = (NLIT + SCAN_T - 1) / SCAN_T;   // 49
    int lo = t * chunk, hi = lo + chunk; if (hi > NLIT) hi = NLIT;
    int s = 0;
    for (int i = lo; i < hi; ++i) s += cnt[i];
    part[t] = s;
    __syncthreads();
    if (t == 0) {
        int run = 0;
        for (int i = 0; i < SCAN_T; ++i) { int v = part[i]; part[i] = run; run += v; }
    }
    __syncthreads();
    int run = part[t];
    for (int i = lo; i < hi; ++i) {
        off[i] = run; cursor[i] = run;
        run += cnt[i];
    }
    if (t == SCAN_T - 1) off[NLIT] = EDGES;
}

__global__ __launch_bounds__(256) void csr_scatter(const int* __restrict__ lit_idx,
                                                   int* __restrict__ cursor,
                                                   int* __restrict__ eidx)
{
    int e = blockIdx.x * 256 + threadIdx.x;
    if (e >= EDGES) return;
    int pos = atomicAdd(&cursor[lit_idx[e]], 1);
    eidx[pos] = e;
}

// -------- gather-based aggregation: agg[lit] = sum of h_c2l over CSR edges --------
__global__ __launch_bounds__(256) void aggregate(const unsigned short* __restrict__ h_c2l,
                                                 const int* __restrict__ off,
                                                 const int* __restrict__ eidx,
                                                 float* __restrict__ agg)
{
    int t = threadIdx.x;
    int lane8 = t & 7;
    int lit = blockIdx.x * 32 + (t >> 3);
    if (lit >= NLIT) return;
    int lo = off[lit], hi = off[lit + 1];
    float s[8] = {0, 0, 0, 0, 0, 0, 0, 0};
    for (int i = lo; i < hi; ++i) {
        int e = eidx[i];
        u16x8 hv = *(const u16x8*)(h_c2l + e * 64 + lane8 * 8);
#pragma unroll
        for (int j = 0; j < 8; ++j) s[j] += bf2f(hv[j]);
    }
    f32x4 a0, a1;
    a0[0] = s[0]; a0[1] = s[1]; a0[2] = s[2]; a0[3] = s[3];
    a1[0] = s[4]; a1[1] = s[5]; a1[2] = s[6]; a1[3] = s[7];
    *(f32x4*)(agg + lit * 64 + lane8 * 8)     = a0;
    *(f32x4*)(agg + lit * 64 + lane8 * 8 + 4) = a1;
}

// -------- init: h = feat @ W_init + b  (bf16) --------
__global__ __launch_bounds__(256) void init_kernel(
    const float* __restrict__ feat_l2c, const float* __restrict__ feat_c2l,
    const float* __restrict__ W_l2c, const float* __restrict__ b_l2c,
    const float* __restrict__ W_c2l, const float* __restrict__ b_c2l,
    unsigned short* __restrict__ h_l2c, unsigned short* __restrict__ h_c2l)
{
    int gid = blockIdx.x * 256 + threadIdx.x;
    if (gid >= EDGES * 8) return;
    int e = gid >> 3, fo = (gid & 7) << 3;
    float2 fl = *(const float2*)(feat_l2c + e * 2);
    float2 fc = *(const float2*)(feat_c2l + e * 2);

    u16x8 outl, outc;
#pragma unroll
    for (int j = 0; j < 8; ++j) {
        float wl0 = W_l2c[fo + j], wl1 = W_l2c[64 + fo + j];
        float wc0 = W_c2l[fo + j], wc1 = W_c2l[64 + fo + j];
        float vl = fl.x * wl0 + fl.y * wl1 + b_l2c[fo + j];
        float vc = fc.x * wc0 + fc.y * wc1 + b_c2l[fo + j];
        outl[j] = f2bf(vl);
        outc[j] = f2bf(vc);
    }
    *(u16x8*)(h_l2c + e * 64 + fo) = outl;
    *(u16x8*)(h_c2l + e * 64 + fo) = outc;
}

// -------- literal update: x0=(agg[lit]-h_c2l)/8 -> MLP3 -> merge(., h_l2c) -> h_l2c --------
__global__ __launch_bounds__(192) void lit_update(
    const unsigned short* __restrict__ h_c2l,
    unsigned short* __restrict__ h_l2c,
    const float* __restrict__ agg,
    const int* __restrict__ lit_idx,
    const unsigned short* __restrict__ wT,
    const float* __restrict__ msgl_b,
    const float* __restrict__ merge_b0,
    const float* __restrict__ merge_br)
{
    __shared__ __align__(16) char lds[3 * 4096];
    int tid = threadIdx.x;
    int wv = tid >> 6, lane = tid & 63;
    int e16 = lane & 15, q = lane >> 4;
    char* ldsw = lds + wv * 4096;
    int base = blockIdx.x * 96 + wv * 32;
    int e_g[2] = { base + e16, base + 16 + e16 };
    int litn[2] = { lit_idx[e_g[0]], lit_idx[e_g[1]] };

    s16x8 bfrag[2][2];
#pragma unroll
    for (int rb = 0; rb < 2; ++rb) {
        int eg = e_g[rb], lit = litn[rb];
#pragma unroll
        for (int kk = 0; kk < 2; ++kk) {
            int f0 = kk * 32 + q * 8;
            const float* ap = agg + lit * 64 + f0;
            f32x4 a0 = *(const f32x4*)ap;
            f32x4 a1 = *(const f32x4*)(ap + 4);
            u16x8 hv = *(const u16x8*)(h_c2l + eg * 64 + f0);
            s16x8 b;
#pragma unroll
            for (int j = 0; j < 4; ++j) b[j]     = (short)f2bf((a0[j] - bf2f(hv[j]))     * 0.125f);
#pragma unroll
            for (int j = 0; j < 4; ++j) b[4 + j] = (short)f2bf((a1[j] - bf2f(hv[4 + j])) * 0.125f);
            bfrag[rb][kk] = b;
        }
    }

    f32x4 acc[2][4];
    layer64(wT + WT_MSGL,        msgl_b,       bfrag, acc, e16, q);
    relayout<true >(acc, bfrag, ldsw, e16, q);
    layer64(wT + WT_MSGL + 4096, msgl_b + 64,  bfrag, acc, e16, q);
    relayout<true >(acc, bfrag, ldsw, e16, q);
    layer64(wT + WT_MSGL + 8192, msgl_b + 128, bfrag, acc, e16, q);
    relayout<false>(acc, bfrag, ldsw, e16, q);        // m fragments

    // h_l2c fragments (read old value before overwrite)
    s16x8 hfrag[2][2];
#pragma unroll
    for (int rb = 0; rb < 2; ++rb)
#pragma unroll
        for (int kk = 0; kk < 2; ++kk)
            hfrag[rb][kk] = *(const s16x8*)(h_l2c + e_g[rb] * 64 + kk * 32 + q * 8);

    // merge layer 0: K=128, [m | h_l2c]
    const unsigned short* w0T = wT + WT_MERGE0;
#pragma unroll
    for (int t = 0; t < 4; ++t) {
        f32x4 bv = *(const f32x4*)(merge_b0 + 16 * t + 4 * q);
        acc[0][t] = bv; acc[1][t] = bv;
    }
#pragma unroll
    for (int t = 0; t < 4; ++t) {
#pragma unroll
        for (int kk = 0; kk < 4; ++kk) {
            s16x8 a = *(const s16x8*)(w0T + (16 * t + e16) * 128 + kk * 32 + q * 8);
            s16x8 b0 = (kk < 2) ? bfrag[0][kk] : hfrag[0][kk - 2];
            s16x8 b1 = (kk < 2) ? bfrag[1][kk] : hfrag[1][kk - 2];
            acc[0][t] = mfma16(a, b0, acc[0][t]);
            acc[1][t] = mfma16(a, b1, acc[1][t]);
        }
    }
    relayout<true>(acc, bfrag, ldsw, e16, q);
    layer64(wT + WT_MERGER,        merge_br,      bfrag, acc, e16, q);
    relayout<true>(acc, bfrag, ldsw, e16, q);
    layer64(wT + WT_MERGER + 4096, merge_br + 64, bfrag, acc, e16, q);

    // store new h_l2c (bf16)
#pragma unroll
    for (int rb = 0; rb < 2; ++rb) {
        int eg = e_g[rb];
#pragma unroll
        for (int t = 0; t < 4; ++t) {
            f32x4 v = acc[rb][t];
            u16x4 p;
            p[0] = f2bf(v[0]); p[1] = f2bf(v[1]); p[2] = f2bf(v[2]); p[3] = f2bf(v[3]);
            *(u16x4*)(h_l2c + eg * 64 + 16 * t + 4 * q) = p;
        }
    }
}

// -------- clause update: x0=(sum of 2 siblings)/8 -> MLP3 -> h_c2l --------
__global__ __launch_bounds__(192) void clause_update(
    const unsigned short* __restrict__ h_l2c,
    unsigned short* __restrict__ h_c2l,
    const unsigned short* __restrict__ msgcT,
    const float* __restrict__ msgc_b)
{
    __shared__ __align__(16) char lds[3 * 4096];
    int tid = threadIdx.x;
    int wv = tid >> 6, lane = tid & 63;
    int e16 = lane & 15, q = lane >> 4;
    char* ldsw = lds + wv * 4096;
    int base = blockIdx.x * 96 + wv * 32;
    int e_g[2] = { base + e16, base + 16 + e16 };

    s16x8 bfrag[2][2];
#pragma unroll
    for (int rb = 0; rb < 2; ++rb) {
        int eg = e_g[rb];
        int c3 = (eg / 3) * 3;
        int d = eg - c3;
        int e1 = c3 + (d == 0 ? 1 : 0);
        int e2 = c3 + (d == 2 ? 1 : 2);
#pragma unroll
        for (int kk = 0; kk < 2; ++kk) {
            int f0 = kk * 32 + q * 8;
            u16x8 h1 = *(const u16x8*)(h_l2c + e1 * 64 + f0);
            u16x8 h2 = *(const u16x8*)(h_l2c + e2 * 64 + f0);
            s16x8 b;
#pragma unroll
            for (int j = 0; j < 8; ++j)
                b[j] = (short)f2bf((bf2f(h1[j]) + bf2f(h2[j])) * 0.125f);
            bfrag[rb][kk] = b;
        }
    }

    f32x4 acc[2][4];
    layer64(msgcT,        msgc_b,       bfrag, acc, e16, q);
    relayout<true>(acc, bfrag, ldsw, e16, q);
    layer64(msgcT + 4096, msgc_b + 64,  bfrag, acc, e16, q);
    relayout<true>(acc, bfrag, ldsw, e16, q);
    layer64(msgcT + 8192, msgc_b + 128, bfrag, acc, e16, q);

#pragma unroll
    for (int rb = 0; rb < 2; ++rb) {
        int eg = e_g[rb];
#pragma unroll
        for (int t = 0; t < 4; ++t) {
            f32x4 v = acc[rb][t];
            u16x4 p;
            p[0] = f2bf(v[0]); p[1] = f2bf(v[1]); p[2] = f2bf(v[2]); p[3] = f2bf(v[3]);
            *(u16x4*)(h_c2l + eg * 64 + 16 * t + 4 * q) = p;
        }
    }
}

// -------- readout stage 1: per-graph sum of h_c2l over contiguous 75000 edges --------
__global__ __launch_bounds__(256) void readout_sum(
    const unsigned short* __restrict__ h_c2l, float* __restrict__ ro_acc)
{
    __shared__ float lsum[32][64];
    int g = blockIdx.x >> 6, chunk = blockIdx.x & 63;
    int t = threadIdx.x;
    int fg = t & 7, el = t >> 3;
    float s[8] = {0, 0, 0, 0, 0, 0, 0, 0};
    for (int idx = chunk * 32 + el; idx < EPG; idx += 2048) {
        u16x8 hv = *(const u16x8*)(h_c2l + (g * EPG + idx) * 64 + fg * 8);
#pragma unroll
        for (int j = 0; j < 8; ++j) s[j] += bf2f(hv[j]);
    }
#pragma unroll
    for (int j = 0; j < 8; ++j) lsum[el][fg * 8 + j] = s[j];
    __syncthreads();
    if (t < 64) {
        float tot = 0.f;
#pragma unroll 8
        for (int r = 0; r < 32; ++r) tot += lsum[r][t];
        atomicAdd(&ro_acc[g * 64 + t], tot);
    }
}

// -------- readout stage 2: tiny MLP + sigmoid --------
__global__ __launch_bounds__(256) void readout_mlp(
    const float* __restrict__ ro_acc, const float* __restrict__ ro_W,
    const float* __restrict__ ro_b, const float* __restrict__ ro_W2,
    const float* __restrict__ ro_b2, float* __restrict__ out)
{
    __shared__ float xb[NGRAPH][HDIM];
    __shared__ float yb[NGRAPH][HDIM];
    int g = threadIdx.x >> 6;
    int j = threadIdx.x & 63;
    xb[g][j] = ro_acc[g * HDIM + j] * (1.0f / 12500.0f);
    __syncthreads();
    float a = ro_b[j];
#pragma unroll 8
    for (int k = 0; k < HDIM; ++k) a += xb[g][k] * ro_W[k * HDIM + j];
    a = fmaxf(a, 0.0f);
    yb[g][j] = a;
    __syncthreads();
    float a2 = ro_b[HDIM + j];
#pragma unroll 8
    for (int k = 0; k < HDIM; ++k) a2 += yb[g][k] * ro_W[4096 + k * HDIM + j];
    a2 = fmaxf(a2, 0.0f);
    float p = a2 * ro_W2[j];
#pragma unroll
    for (int off = 32; off > 0; off >>= 1) p += __shfl_down(p, off, 64);
    if (j == 0) out[g] = 1.0f / (1.0f + expf(-(p + ro_b2[0])));
}

extern "C" void kernel_launch(void* const* d_in, const int* in_sizes, int n_in,
                              void* d_out, int out_size, void* d_ws, size_t ws_size,
                              hipStream_t stream)
{
    const float* feat_l2c = (const float*)d_in[0];
    const float* feat_c2l = (const float*)d_in[1];
    const int*   lit_idx  = (const int*)d_in[2];
    // d_in[3] (cls_idx) unused: edges are clause-major by construction
    const float* W_l2c    = (const float*)d_in[4];
    const float* b_l2c    = (const float*)d_in[5];
    const float* W_c2l    = (const float*)d_in[6];
    const float* b_c2l    = (const float*)d_in[7];
    const float* msgl_W   = (const float*)d_in[8];
    const float* msgl_b   = (const float*)d_in[9];
    const float* merge_W0 = (const float*)d_in[10];
    const float* merge_b0 = (const float*)d_in[11];
    const float* merge_Wr = (const float*)d_in[12];
    const float* merge_br = (const float*)d_in[13];
    const float* msgc_W   = (const float*)d_in[14];
    const float* msgc_b   = (const float*)d_in[15];
    const float* ro_W     = (const float*)d_in[16];
    const float* ro_b     = (const float*)d_in[17];
    const float* ro_W2    = (const float*)d_in[18];
    const float* ro_b2    = (const float*)d_in[19];

    char* ws = (char*)d_ws;
    unsigned short* h_l2c  = (unsigned short*)(ws + OFF_HL2C);
    unsigned short* h_c2l  = (unsigned short*)(ws + OFF_HC2L);
    float*          agg    = (float*)(ws + OFF_AGG);
    unsigned short* wT     = (unsigned short*)(ws + OFF_WT);
    float*          ro_acc = (float*)(ws + OFF_ROACC);
    int*            cnt    = (int*)(ws + OFF_CNT);
    int*            csroff = (int*)(ws + OFF_CSROFF);
    int*            cursor = (int*)(ws + OFF_CURSOR);
    int*            eidx   = (int*)(ws + OFF_EIDX);

    hipMemsetAsync(cnt, 0, NLIT * sizeof(int), stream);
    hipMemsetAsync(ro_acc, 0, NGRAPH * 64 * sizeof(float), stream);

    prep_weights<<<(WT_TOTAL + 255) / 256, 256, 0, stream>>>(msgl_W, merge_W0, merge_Wr, msgc_W, wT);

    // CSR of lit_idx (per-launch rebuild; ~15 us)
    csr_hist<<<(EDGES + 255) / 256, 256, 0, stream>>>(lit_idx, cnt);
    csr_scan<<<1, SCAN_T, 0, stream>>>(cnt, csroff, cursor);
    csr_scatter<<<(EDGES + 255) / 256, 256, 0, stream>>>(lit_idx, cursor, eidx);

    init_kernel<<<EDGES * 8 / 256, 256, 0, stream>>>(feat_l2c, feat_c2l, W_l2c, b_l2c,
                                                     W_c2l, b_c2l, h_l2c, h_c2l);
    for (int r = 0; r < 3; ++r) {
        aggregate<<<(NLIT + 31) / 32, 256, 0, stream>>>(h_c2l, csroff, eidx, agg);
        lit_update<<<EDGES / 96, 192, 0, stream>>>(h_c2l, h_l2c, agg, lit_idx, wT,
                                                   msgl_b, merge_b0, merge_br);
        clause_update<<<EDGES / 96, 192, 0, stream>>>(h_l2c, h_c2l, wT + WT_MSGC, msgc_b);
    }
    readout_sum<<<256, 256, 0, stream>>>(h_c2l, ro_acc);
    readout_mlp<<<1, 256, 0, stream>>>(ro_acc, ro_W, ro_b, ro_W2, ro_b2, (float*)d_out);
}

// Round 3
// 560.455 us; speedup vs baseline: 2.6372x; 1.1939x over previous
//
#include <hip/hip_runtime.h>
#include <stdint.h>

// ---------------- problem constants ----------------
#define EDGES   300000
#define NLIT    50000
#define NGRAPH  4
#define EPG     75000          // edges per graph (contiguous)
#define HDIM    64

// ws layout (bytes)
#define OFF_HL2C   0
#define OFF_HC2L   38400000
#define OFF_AGG    76800000
#define OFF_WT     89600000
#define OFF_ROACC  89681920
#define OFF_CNT    89682944
#define OFF_CSROFF 89882944
#define OFF_CURSOR 90082948
#define OFF_EIDX   90282948
#define OFF_BSUM   91482948
#define OFF_BBASE  91484000
// end ~91.5 MB

// weight-T element offsets within wT (bf16 elements)
#define WT_MSGL    0          // [3][64][64]
#define WT_MERGE0  12288      // [64][128]
#define WT_MERGER  20480      // [2][64][64]
#define WT_MSGC    28672      // [3][64][64]
#define WT_TOTAL   40960

#define SCAN_BLOCKS ((NLIT + 255) / 256)   // 196

typedef __attribute__((ext_vector_type(8))) short          s16x8;
typedef __attribute__((ext_vector_type(8))) unsigned short u16x8;
typedef __attribute__((ext_vector_type(4))) unsigned short u16x4;
typedef __attribute__((ext_vector_type(4))) float          f32x4;

__device__ __forceinline__ f32x4 mfma16(s16x8 a, s16x8 b, f32x4 c) {
    return __builtin_amdgcn_mfma_f32_16x16x32_bf16(a, b, c, 0, 0, 0);
}
__device__ __forceinline__ float bf2f(unsigned short s) {
    union { unsigned int u; float f; } v; v.u = ((unsigned int)s) << 16; return v.f;
}
__device__ __forceinline__ unsigned short f2bf(float f) {
    union { float f; unsigned int u; } v; v.f = f;
    return (unsigned short)((v.u + 0x7fffu + ((v.u >> 16) & 1u)) >> 16);
}

// one 64->64 layer: acc[rb][t] = bias + W^T @ bin   (D[f][e] orientation)
__device__ __forceinline__ void layer64(const unsigned short* __restrict__ wT,
                                        const float* __restrict__ bias,
                                        const s16x8 (&bin)[2][2],
                                        f32x4 (&acc)[2][4],
                                        int e16, int q)
{
#pragma unroll
    for (int t = 0; t < 4; ++t) {
        f32x4 bv = *(const f32x4*)(bias + 16 * t + 4 * q);
        acc[0][t] = bv; acc[1][t] = bv;
    }
#pragma unroll
    for (int t = 0; t < 4; ++t) {
#pragma unroll
        for (int kk = 0; kk < 2; ++kk) {
            s16x8 a = *(const s16x8*)(wT + (16 * t + e16) * 64 + kk * 32 + q * 8);
            acc[0][t] = mfma16(a, bin[0][kk], acc[0][t]);
            acc[1][t] = mfma16(a, bin[1][kk], acc[1][t]);
        }
    }
}

// C-layout acc -> B-fragments for next layer via swizzled per-wave LDS tile [32][64] bf16
template<bool RELU>
__device__ __forceinline__ void relayout(const f32x4 (&acc)[2][4], s16x8 (&out)[2][2],
                                         char* __restrict__ ldsw, int e16, int q)
{
#pragma unroll
    for (int rb = 0; rb < 2; ++rb) {
        int e = rb * 16 + e16;
        int rowoff = e * 128;
        int sw = (e & 7) << 4;
#pragma unroll
        for (int t = 0; t < 4; ++t) {
            f32x4 v = acc[rb][t];
            if (RELU) {
                v[0] = fmaxf(v[0], 0.f); v[1] = fmaxf(v[1], 0.f);
                v[2] = fmaxf(v[2], 0.f); v[3] = fmaxf(v[3], 0.f);
            }
            u16x4 p;
            p[0] = f2bf(v[0]); p[1] = f2bf(v[1]); p[2] = f2bf(v[2]); p[3] = f2bf(v[3]);
            *(u16x4*)(ldsw + rowoff + ((32 * t + 8 * q) ^ sw)) = p;
        }
    }
    asm volatile("s_waitcnt lgkmcnt(0)" ::: "memory");
    __builtin_amdgcn_sched_barrier(0);
#pragma unroll
    for (int rb = 0; rb < 2; ++rb) {
        int e = rb * 16 + e16;
        int rowoff = e * 128;
        int sw = (e & 7) << 4;
#pragma unroll
        for (int kk = 0; kk < 2; ++kk)
            out[rb][kk] = *(const s16x8*)(ldsw + rowoff + ((64 * kk + 16 * q) ^ sw));
    }
}

// -------- transpose + bf16-convert all round weights into ws --------
__global__ __launch_bounds__(256) void prep_weights(
    const float* __restrict__ msgl_W, const float* __restrict__ merge_W0,
    const float* __restrict__ merge_Wr, const float* __restrict__ msgc_W,
    unsigned short* __restrict__ wT)
{
    int gid = blockIdx.x * 256 + threadIdx.x;
    if (gid >= WT_TOTAL) return;
    float v;
    if (gid < WT_MERGE0) {                       // msglT [3][out][in]
        int m = gid >> 12, idx = gid & 4095, o = idx >> 6, i = idx & 63;
        v = msgl_W[(m << 12) + i * 64 + o];
    } else if (gid < WT_MERGER) {                // mergeW0T [64][128]
        int idx = gid - WT_MERGE0, o = idx >> 7, i = idx & 127;
        v = merge_W0[i * 64 + o];
    } else if (gid < WT_MSGC) {                  // mergeWrT [2][out][in]
        int idx = gid - WT_MERGER, m = idx >> 12, j = idx & 4095, o = j >> 6, i = j & 63;
        v = merge_Wr[(m << 12) + i * 64 + o];
    } else {                                     // msgcT [3][out][in]
        int idx = gid - WT_MSGC, m = idx >> 12, j = idx & 4095, o = j >> 6, i = j & 63;
        v = msgc_W[(m << 12) + i * 64 + o];
    }
    wT[gid] = f2bf(v);
}

// -------- CSR build: histogram -> 3-stage parallel scan -> scatter --------
__global__ __launch_bounds__(256) void csr_hist(const int* __restrict__ lit_idx,
                                                int* __restrict__ cnt)
{
    int e = blockIdx.x * 256 + threadIdx.x;
    if (e < EDGES) atomicAdd(&cnt[lit_idx[e]], 1);
}

__global__ __launch_bounds__(256) void scan1(const int* __restrict__ cnt,
                                             int* __restrict__ bsum)
{
    __shared__ int red[4];
    int i = blockIdx.x * 256 + threadIdx.x;
    int s = (i < NLIT) ? cnt[i] : 0;
#pragma unroll
    for (int off = 1; off < 64; off <<= 1) s += __shfl_xor(s, off, 64);
    if ((threadIdx.x & 63) == 0) red[threadIdx.x >> 6] = s;
    __syncthreads();
    if (threadIdx.x == 0) bsum[blockIdx.x] = red[0] + red[1] + red[2] + red[3];
}

__global__ __launch_bounds__(256) void scan2(const int* __restrict__ bsum,
                                             int* __restrict__ bbase)
{
    __shared__ int tmp[256];
    int t = threadIdx.x;
    int v = (t < SCAN_BLOCKS) ? bsum[t] : 0;
    tmp[t] = v;
    __syncthreads();
#pragma unroll
    for (int off = 1; off < 256; off <<= 1) {
        int add = (t >= off) ? tmp[t - off] : 0;
        __syncthreads();
        tmp[t] += add;
        __syncthreads();
    }
    if (t < SCAN_BLOCKS) bbase[t] = tmp[t] - v;   // exclusive
}

__global__ __launch_bounds__(256) void scan3(const int* __restrict__ cnt,
                                             const int* __restrict__ bbase,
                                             int* __restrict__ off,
                                             int* __restrict__ cursor)
{
    __shared__ int tmp[256];
    int t = threadIdx.x;
    int i = blockIdx.x * 256 + t;
    int v = (i < NLIT) ? cnt[i] : 0;
    tmp[t] = v;
    __syncthreads();
#pragma unroll
    for (int offs = 1; offs < 256; offs <<= 1) {
        int add = (t >= offs) ? tmp[t - offs] : 0;
        __syncthreads();
        tmp[t] += add;
        __syncthreads();
    }
    if (i < NLIT) {
        int ex = bbase[blockIdx.x] + tmp[t] - v;
        off[i] = ex; cursor[i] = ex;
    }
    if (i == NLIT - 1) off[NLIT] = EDGES;
}

__global__ __launch_bounds__(256) void csr_scatter(const int* __restrict__ lit_idx,
                                                   int* __restrict__ cursor,
                                                   int* __restrict__ eidx)
{
    int e = blockIdx.x * 256 + threadIdx.x;
    if (e >= EDGES) return;
    int pos = atomicAdd(&cursor[lit_idx[e]], 1);
    eidx[pos] = e;
}

// -------- gather-based aggregation: agg[lit] = sum of h_c2l over CSR edges --------
__global__ __launch_bounds__(256) void aggregate(const unsigned short* __restrict__ h_c2l,
                                                 const int* __restrict__ off,
                                                 const int* __restrict__ eidx,
                                                 float* __restrict__ agg)
{
    int t = threadIdx.x;
    int lane8 = t & 7;
    int lit = blockIdx.x * 32 + (t >> 3);
    if (lit >= NLIT) return;
    int lo = off[lit], hi = off[lit + 1];
    float s[8] = {0, 0, 0, 0, 0, 0, 0, 0};
    for (int i = lo; i < hi; ++i) {
        int e = eidx[i];
        u16x8 hv = *(const u16x8*)(h_c2l + e * 64 + lane8 * 8);
#pragma unroll
        for (int j = 0; j < 8; ++j) s[j] += bf2f(hv[j]);
    }
    f32x4 a0, a1;
    a0[0] = s[0]; a0[1] = s[1]; a0[2] = s[2]; a0[3] = s[3];
    a1[0] = s[4]; a1[1] = s[5]; a1[2] = s[6]; a1[3] = s[7];
    *(f32x4*)(agg + lit * 64 + lane8 * 8)     = a0;
    *(f32x4*)(agg + lit * 64 + lane8 * 8 + 4) = a1;
}

// -------- init: h = feat @ W_init + b  (bf16) --------
__global__ __launch_bounds__(256) void init_kernel(
    const float* __restrict__ feat_l2c, const float* __restrict__ feat_c2l,
    const float* __restrict__ W_l2c, const float* __restrict__ b_l2c,
    const float* __restrict__ W_c2l, const float* __restrict__ b_c2l,
    unsigned short* __restrict__ h_l2c, unsigned short* __restrict__ h_c2l)
{
    int gid = blockIdx.x * 256 + threadIdx.x;
    if (gid >= EDGES * 8) return;
    int e = gid >> 3, fo = (gid & 7) << 3;
    float2 fl = *(const float2*)(feat_l2c + e * 2);
    float2 fc = *(const float2*)(feat_c2l + e * 2);

    u16x8 outl, outc;
#pragma unroll
    for (int j = 0; j < 8; ++j) {
        float wl0 = W_l2c[fo + j], wl1 = W_l2c[64 + fo + j];
        float wc0 = W_c2l[fo + j], wc1 = W_c2l[64 + fo + j];
        float vl = fl.x * wl0 + fl.y * wl1 + b_l2c[fo + j];
        float vc = fc.x * wc0 + fc.y * wc1 + b_c2l[fo + j];
        outl[j] = f2bf(vl);
        outc[j] = f2bf(vc);
    }
    *(u16x8*)(h_l2c + e * 64 + fo) = outl;
    *(u16x8*)(h_c2l + e * 64 + fo) = outc;
}

// -------- literal update: x0=(agg[lit]-h_c2l)/8 -> MLP3 -> merge(., h_l2c) -> h_l2c --------
__global__ __launch_bounds__(192) void lit_update(
    const unsigned short* __restrict__ h_c2l,
    unsigned short* __restrict__ h_l2c,
    const float* __restrict__ agg,
    const int* __restrict__ lit_idx,
    const unsigned short* __restrict__ wT,
    const float* __restrict__ msgl_b,
    const float* __restrict__ merge_b0,
    const float* __restrict__ merge_br)
{
    __shared__ __align__(16) char lds[3 * 4096];
    int tid = threadIdx.x;
    int wv = tid >> 6, lane = tid & 63;
    int e16 = lane & 15, q = lane >> 4;
    char* ldsw = lds + wv * 4096;
    int base = blockIdx.x * 96 + wv * 32;
    int e_g[2] = { base + e16, base + 16 + e16 };
    int litn[2] = { lit_idx[e_g[0]], lit_idx[e_g[1]] };

    s16x8 bfrag[2][2];
#pragma unroll
    for (int rb = 0; rb < 2; ++rb) {
        int eg = e_g[rb], lit = litn[rb];
#pragma unroll
        for (int kk = 0; kk < 2; ++kk) {
            int f0 = kk * 32 + q * 8;
            const float* ap = agg + lit * 64 + f0;
            f32x4 a0 = *(const f32x4*)ap;
            f32x4 a1 = *(const f32x4*)(ap + 4);
            u16x8 hv = *(const u16x8*)(h_c2l + eg * 64 + f0);
            s16x8 b;
#pragma unroll
            for (int j = 0; j < 4; ++j) b[j]     = (short)f2bf((a0[j] - bf2f(hv[j]))     * 0.125f);
#pragma unroll
            for (int j = 0; j < 4; ++j) b[4 + j] = (short)f2bf((a1[j] - bf2f(hv[4 + j])) * 0.125f);
            bfrag[rb][kk] = b;
        }
    }

    f32x4 acc[2][4];
    layer64(wT + WT_MSGL,        msgl_b,       bfrag, acc, e16, q);
    relayout<true >(acc, bfrag, ldsw, e16, q);
    layer64(wT + WT_MSGL + 4096, msgl_b + 64,  bfrag, acc, e16, q);
    relayout<true >(acc, bfrag, ldsw, e16, q);
    layer64(wT + WT_MSGL + 8192, msgl_b + 128, bfrag, acc, e16, q);
    relayout<false>(acc, bfrag, ldsw, e16, q);        // m fragments

    // h_l2c fragments (read old value before overwrite)
    s16x8 hfrag[2][2];
#pragma unroll
    for (int rb = 0; rb < 2; ++rb)
#pragma unroll
        for (int kk = 0; kk < 2; ++kk)
            hfrag[rb][kk] = *(const s16x8*)(h_l2c + e_g[rb] * 64 + kk * 32 + q * 8);

    // merge layer 0: K=128, [m | h_l2c]
    const unsigned short* w0T = wT + WT_MERGE0;
#pragma unroll
    for (int t = 0; t < 4; ++t) {
        f32x4 bv = *(const f32x4*)(merge_b0 + 16 * t + 4 * q);
        acc[0][t] = bv; acc[1][t] = bv;
    }
#pragma unroll
    for (int t = 0; t < 4; ++t) {
#pragma unroll
        for (int kk = 0; kk < 4; ++kk) {
            s16x8 a = *(const s16x8*)(w0T + (16 * t + e16) * 128 + kk * 32 + q * 8);
            s16x8 b0 = (kk < 2) ? bfrag[0][kk] : hfrag[0][kk - 2];
            s16x8 b1 = (kk < 2) ? bfrag[1][kk] : hfrag[1][kk - 2];
            acc[0][t] = mfma16(a, b0, acc[0][t]);
            acc[1][t] = mfma16(a, b1, acc[1][t]);
        }
    }
    relayout<true>(acc, bfrag, ldsw, e16, q);
    layer64(wT + WT_MERGER,        merge_br,      bfrag, acc, e16, q);
    relayout<true>(acc, bfrag, ldsw, e16, q);
    layer64(wT + WT_MERGER + 4096, merge_br + 64, bfrag, acc, e16, q);

    // store new h_l2c (bf16)
#pragma unroll
    for (int rb = 0; rb < 2; ++rb) {
        int eg = e_g[rb];
#pragma unroll
        for (int t = 0; t < 4; ++t) {
            f32x4 v = acc[rb][t];
            u16x4 p;
            p[0] = f2bf(v[0]); p[1] = f2bf(v[1]); p[2] = f2bf(v[2]); p[3] = f2bf(v[3]);
            *(u16x4*)(h_l2c + eg * 64 + 16 * t + 4 * q) = p;
        }
    }
}

// -------- clause update: x0=(sum of 2 siblings)/8 -> MLP3 -> h_c2l --------
__global__ __launch_bounds__(192) void clause_update(
    const unsigned short* __restrict__ h_l2c,
    unsigned short* __restrict__ h_c2l,
    const unsigned short* __restrict__ msgcT,
    const float* __restrict__ msgc_b)
{
    __shared__ __align__(16) char lds[3 * 4096];
    int tid = threadIdx.x;
    int wv = tid >> 6, lane = tid & 63;
    int e16 = lane & 15, q = lane >> 4;
    char* ldsw = lds + wv * 4096;
    int base = blockIdx.x * 96 + wv * 32;
    int e_g[2] = { base + e16, base + 16 + e16 };

    s16x8 bfrag[2][2];
#pragma unroll
    for (int rb = 0; rb < 2; ++rb) {
        int eg = e_g[rb];
        int c3 = (eg / 3) * 3;
        int d = eg - c3;
        int e1 = c3 + (d == 0 ? 1 : 0);
        int e2 = c3 + (d == 2 ? 1 : 2);
#pragma unroll
        for (int kk = 0; kk < 2; ++kk) {
            int f0 = kk * 32 + q * 8;
            u16x8 h1 = *(const u16x8*)(h_l2c + e1 * 64 + f0);
            u16x8 h2 = *(const u16x8*)(h_l2c + e2 * 64 + f0);
            s16x8 b;
#pragma unroll
            for (int j = 0; j < 8; ++j)
                b[j] = (short)f2bf((bf2f(h1[j]) + bf2f(h2[j])) * 0.125f);
            bfrag[rb][kk] = b;
        }
    }

    f32x4 acc[2][4];
    layer64(msgcT,        msgc_b,       bfrag, acc, e16, q);
    relayout<true>(acc, bfrag, ldsw, e16, q);
    layer64(msgcT + 4096, msgc_b + 64,  bfrag, acc, e16, q);
    relayout<true>(acc, bfrag, ldsw, e16, q);
    layer64(msgcT + 8192, msgc_b + 128, bfrag, acc, e16, q);

#pragma unroll
    for (int rb = 0; rb < 2; ++rb) {
        int eg = e_g[rb];
#pragma unroll
        for (int t = 0; t < 4; ++t) {
            f32x4 v = acc[rb][t];
            u16x4 p;
            p[0] = f2bf(v[0]); p[1] = f2bf(v[1]); p[2] = f2bf(v[2]); p[3] = f2bf(v[3]);
            *(u16x4*)(h_c2l + eg * 64 + 16 * t + 4 * q) = p;
        }
    }
}

// -------- readout stage 1: per-graph sum of h_c2l over contiguous 75000 edges --------
__global__ __launch_bounds__(256) void readout_sum(
    const unsigned short* __restrict__ h_c2l, float* __restrict__ ro_acc)
{
    __shared__ float lsum[32][64];
    int g = blockIdx.x >> 6, chunk = blockIdx.x & 63;
    int t = threadIdx.x;
    int fg = t & 7, el = t >> 3;
    float s[8] = {0, 0, 0, 0, 0, 0, 0, 0};
    for (int idx = chunk * 32 + el; idx < EPG; idx += 2048) {
        u16x8 hv = *(const u16x8*)(h_c2l + (g * EPG + idx) * 64 + fg * 8);
#pragma unroll
        for (int j = 0; j < 8; ++j) s[j] += bf2f(hv[j]);
    }
#pragma unroll
    for (int j = 0; j < 8; ++j) lsum[el][fg * 8 + j] = s[j];
    __syncthreads();
    if (t < 64) {
        float tot = 0.f;
#pragma unroll 8
        for (int r = 0; r < 32; ++r) tot += lsum[r][t];
        atomicAdd(&ro_acc[g * 64 + t], tot);
    }
}

// -------- readout stage 2: tiny MLP + sigmoid --------
__global__ __launch_bounds__(256) void readout_mlp(
    const float* __restrict__ ro_acc, const float* __restrict__ ro_W,
    const float* __restrict__ ro_b, const float* __restrict__ ro_W2,
    const float* __restrict__ ro_b2, float* __restrict__ out)
{
    __shared__ float xb[NGRAPH][HDIM];
    __shared__ float yb[NGRAPH][HDIM];
    int g = threadIdx.x >> 6;
    int j = threadIdx.x & 63;
    xb[g][j] = ro_acc[g * HDIM + j] * (1.0f / 12500.0f);
    __syncthreads();
    float a = ro_b[j];
#pragma unroll 8
    for (int k = 0; k < HDIM; ++k) a += xb[g][k] * ro_W[k * HDIM + j];
    a = fmaxf(a, 0.0f);
    yb[g][j] = a;
    __syncthreads();
    float a2 = ro_b[HDIM + j];
#pragma unroll 8
    for (int k = 0; k < HDIM; ++k) a2 += yb[g][k] * ro_W[4096 + k * HDIM + j];
    a2 = fmaxf(a2, 0.0f);
    float p = a2 * ro_W2[j];
#pragma unroll
    for (int off = 32; off > 0; off >>= 1) p += __shfl_down(p, off, 64);
    if (j == 0) out[g] = 1.0f / (1.0f + expf(-(p + ro_b2[0])));
}

extern "C" void kernel_launch(void* const* d_in, const int* in_sizes, int n_in,
                              void* d_out, int out_size, void* d_ws, size_t ws_size,
                              hipStream_t stream)
{
    const float* feat_l2c = (const float*)d_in[0];
    const float* feat_c2l = (const float*)d_in[1];
    const int*   lit_idx  = (const int*)d_in[2];
    // d_in[3] (cls_idx) unused: edges are clause-major by construction
    const float* W_l2c    = (const float*)d_in[4];
    const float* b_l2c    = (const float*)d_in[5];
    const float* W_c2l    = (const float*)d_in[6];
    const float* b_c2l    = (const float*)d_in[7];
    const float* msgl_W   = (const float*)d_in[8];
    const float* msgl_b   = (const float*)d_in[9];
    const float* merge_W0 = (const float*)d_in[10];
    const float* merge_b0 = (const float*)d_in[11];
    const float* merge_Wr = (const float*)d_in[12];
    const float* merge_br = (const float*)d_in[13];
    const float* msgc_W   = (const float*)d_in[14];
    const float* msgc_b   = (const float*)d_in[15];
    const float* ro_W     = (const float*)d_in[16];
    const float* ro_b     = (const float*)d_in[17];
    const float* ro_W2    = (const float*)d_in[18];
    const float* ro_b2    = (const float*)d_in[19];

    char* ws = (char*)d_ws;
    unsigned short* h_l2c  = (unsigned short*)(ws + OFF_HL2C);
    unsigned short* h_c2l  = (unsigned short*)(ws + OFF_HC2L);
    float*          agg    = (float*)(ws + OFF_AGG);
    unsigned short* wT     = (unsigned short*)(ws + OFF_WT);
    float*          ro_acc = (float*)(ws + OFF_ROACC);
    int*            cnt    = (int*)(ws + OFF_CNT);
    int*            csroff = (int*)(ws + OFF_CSROFF);
    int*            cursor = (int*)(ws + OFF_CURSOR);
    int*            eidx   = (int*)(ws + OFF_EIDX);
    int*            bsum   = (int*)(ws + OFF_BSUM);
    int*            bbase  = (int*)(ws + OFF_BBASE);

    hipMemsetAsync(cnt, 0, NLIT * sizeof(int), stream);
    hipMemsetAsync(ro_acc, 0, NGRAPH * 64 * sizeof(float), stream);

    prep_weights<<<(WT_TOTAL + 255) / 256, 256, 0, stream>>>(msgl_W, merge_W0, merge_Wr, msgc_W, wT);

    // CSR of lit_idx (per-launch rebuild; 3-stage parallel scan)
    csr_hist<<<(EDGES + 255) / 256, 256, 0, stream>>>(lit_idx, cnt);
    scan1<<<SCAN_BLOCKS, 256, 0, stream>>>(cnt, bsum);
    scan2<<<1, 256, 0, stream>>>(bsum, bbase);
    scan3<<<SCAN_BLOCKS, 256, 0, stream>>>(cnt, bbase, csroff, cursor);
    csr_scatter<<<(EDGES + 255) / 256, 256, 0, stream>>>(lit_idx, cursor, eidx);

    init_kernel<<<EDGES * 8 / 256, 256, 0, stream>>>(feat_l2c, feat_c2l, W_l2c, b_l2c,
                                                     W_c2l, b_c2l, h_l2c, h_c2l);
    for (int r = 0; r < 3; ++r) {
        aggregate<<<(NLIT + 31) / 32, 256, 0, stream>>>(h_c2l, csroff, eidx, agg);
        lit_update<<<EDGES / 96, 192, 0, stream>>>(h_c2l, h_l2c, agg, lit_idx, wT,
                                                   msgl_b, merge_b0, merge_br);
        clause_update<<<EDGES / 96, 192, 0, stream>>>(h_l2c, h_c2l, wT + WT_MSGC, msgc_b);
    }
    readout_sum<<<256, 256, 0, stream>>>(h_c2l, ro_acc);
    readout_mlp<<<1, 256, 0, stream>>>(ro_acc, ro_W, ro_b, ro_W2, ro_b2, (float*)d_out);
}

// Round 4
// 444.545 us; speedup vs baseline: 3.3248x; 1.2607x over previous
//
#include <hip/hip_runtime.h>
#include <stdint.h>

// ---------------- problem constants ----------------
#define EDGES   300000
#define NLIT    50000
#define NGRAPH  4
#define EPG     75000          // edges per graph (contiguous)
#define HDIM    64

// ws layout (bytes)
#define OFF_HL2C   0
#define OFF_HC2L   38400000
#define OFF_AGG    76800000
#define OFF_WT     89600000
#define OFF_ROACC  89681920
#define OFF_CNT    89682944
#define OFF_CSROFF 89882944
#define OFF_CURSOR 90082948
#define OFF_EIDX   90282948
#define OFF_BSUM   91482948
#define OFF_BBASE  91484000
// end ~91.5 MB

// wT global layout: 10 "units", each [64 rows=out][64 cols=in] bf16 (4096 elems).
// u0-2: msglT ; u3: merge0T cols 0-63 (m part) ; u4: merge0T cols 64-127 (h part)
// u5-6: mergeRT ; u7-9: msgcT
#define WT_TOTAL   40960
#define WT_CLS_ELEM 28672      // element offset of clause units (u7)

#define WAVES_PB   6
#define EPB        (WAVES_PB * 32)            // 192 edges per block
#define GRID_EDGE  ((EDGES + EPB - 1) / EPB)  // 1563

#define LIT_WBYTES (7 * 8192)   // 57344
#define CLS_WBYTES (3 * 8192)   // 24576

#define SCAN_BLOCKS ((NLIT + 255) / 256)   // 196

typedef __attribute__((ext_vector_type(8))) short          s16x8;
typedef __attribute__((ext_vector_type(8))) unsigned short u16x8;
typedef __attribute__((ext_vector_type(4))) unsigned short u16x4;
typedef __attribute__((ext_vector_type(4))) float          f32x4;

__device__ __forceinline__ f32x4 mfma16(s16x8 a, s16x8 b, f32x4 c) {
    return __builtin_amdgcn_mfma_f32_16x16x32_bf16(a, b, c, 0, 0, 0);
}
__device__ __forceinline__ float bf2f(unsigned short s) {
    union { unsigned int u; float f; } v; v.u = ((unsigned int)s) << 16; return v.f;
}
__device__ __forceinline__ unsigned short f2bf(float f) {
    union { float f; unsigned int u; } v; v.f = f;
    return (unsigned short)((v.u + 0x7fffu + ((v.u >> 16) & 1u)) >> 16);
}

// stage nchunks 16B chunks of unit-layout weights into LDS with XOR swizzle
__device__ __forceinline__ void stage_weights(const unsigned short* __restrict__ wsrc,
                                              char* __restrict__ ldsW,
                                              int nchunks, int tid, int nthreads)
{
    for (int c = tid; c < nchunks; c += nthreads) {
        u16x8 v = *(const u16x8*)(wsrc + c * 8);
        int u = c >> 9;               // 512 chunks per unit
        int row = (c >> 3) & 63;
        int slot = c & 7;
        *(u16x8*)(ldsW + u * 8192 + row * 128 + ((slot * 16) ^ ((row & 7) << 4))) = v;
    }
}

// one 64->64 layer from an LDS weight unit: acc[rb][t] = bias + W^T @ bin
__device__ __forceinline__ void layer64_lds(const char* __restrict__ unitBase,
                                            const float* __restrict__ bias,
                                            const s16x8 (&bin)[2][2],
                                            f32x4 (&acc)[2][4],
                                            int e16, int q)
{
#pragma unroll
    for (int t = 0; t < 4; ++t) {
        f32x4 bv = *(const f32x4*)(bias + 16 * t + 4 * q);
        acc[0][t] = bv; acc[1][t] = bv;
    }
#pragma unroll
    for (int t = 0; t < 4; ++t) {
        int row = 16 * t + e16;
#pragma unroll
        for (int kk = 0; kk < 2; ++kk) {
            s16x8 a = *(const s16x8*)(unitBase + row * 128 +
                                      ((kk * 64 + q * 16) ^ ((row & 7) << 4)));
            acc[0][t] = mfma16(a, bin[0][kk], acc[0][t]);
            acc[1][t] = mfma16(a, bin[1][kk], acc[1][t]);
        }
    }
}

// C-layout acc -> B-fragments for next layer via swizzled per-wave LDS tile [32][64] bf16
template<bool RELU>
__device__ __forceinline__ void relayout(const f32x4 (&acc)[2][4], s16x8 (&out)[2][2],
                                         char* __restrict__ ldsw, int e16, int q)
{
#pragma unroll
    for (int rb = 0; rb < 2; ++rb) {
        int e = rb * 16 + e16;
        int rowoff = e * 128;
        int sw = (e & 7) << 4;
#pragma unroll
        for (int t = 0; t < 4; ++t) {
            f32x4 v = acc[rb][t];
            if (RELU) {
                v[0] = fmaxf(v[0], 0.f); v[1] = fmaxf(v[1], 0.f);
                v[2] = fmaxf(v[2], 0.f); v[3] = fmaxf(v[3], 0.f);
            }
            u16x4 p;
            p[0] = f2bf(v[0]); p[1] = f2bf(v[1]); p[2] = f2bf(v[2]); p[3] = f2bf(v[3]);
            *(u16x4*)(ldsw + rowoff + ((32 * t + 8 * q) ^ sw)) = p;
        }
    }
    asm volatile("s_waitcnt lgkmcnt(0)" ::: "memory");
    __builtin_amdgcn_sched_barrier(0);
#pragma unroll
    for (int rb = 0; rb < 2; ++rb) {
        int e = rb * 16 + e16;
        int rowoff = e * 128;
        int sw = (e & 7) << 4;
#pragma unroll
        for (int kk = 0; kk < 2; ++kk)
            out[rb][kk] = *(const s16x8*)(ldsw + rowoff + ((64 * kk + 16 * q) ^ sw));
    }
}

// -------- transpose + bf16-convert all round weights into unit layout --------
__global__ __launch_bounds__(256) void prep_weights(
    const float* __restrict__ msgl_W, const float* __restrict__ merge_W0,
    const float* __restrict__ merge_Wr, const float* __restrict__ msgc_W,
    unsigned short* __restrict__ wT)
{
    int gid = blockIdx.x * 256 + threadIdx.x;
    if (gid >= WT_TOTAL) return;
    int unit = gid >> 12;
    int o = (gid >> 6) & 63, i = gid & 63;
    float v;
    if (unit < 3)       v = msgl_W[unit * 4096 + i * 64 + o];
    else if (unit < 5)  v = merge_W0[((unit - 3) * 64 + i) * 64 + o];
    else if (unit < 7)  v = merge_Wr[(unit - 5) * 4096 + i * 64 + o];
    else                v = msgc_W[(unit - 7) * 4096 + i * 64 + o];
    wT[gid] = f2bf(v);
}

// -------- CSR build: histogram -> 3-stage parallel scan -> scatter --------
__global__ __launch_bounds__(256) void csr_hist(const int* __restrict__ lit_idx,
                                                int* __restrict__ cnt)
{
    int e = blockIdx.x * 256 + threadIdx.x;
    if (e < EDGES) atomicAdd(&cnt[lit_idx[e]], 1);
}

__global__ __launch_bounds__(256) void scan1(const int* __restrict__ cnt,
                                             int* __restrict__ bsum)
{
    __shared__ int red[4];
    int i = blockIdx.x * 256 + threadIdx.x;
    int s = (i < NLIT) ? cnt[i] : 0;
#pragma unroll
    for (int off = 1; off < 64; off <<= 1) s += __shfl_xor(s, off, 64);
    if ((threadIdx.x & 63) == 0) red[threadIdx.x >> 6] = s;
    __syncthreads();
    if (threadIdx.x == 0) bsum[blockIdx.x] = red[0] + red[1] + red[2] + red[3];
}

__global__ __launch_bounds__(256) void scan2(const int* __restrict__ bsum,
                                             int* __restrict__ bbase)
{
    __shared__ int tmp[256];
    int t = threadIdx.x;
    int v = (t < SCAN_BLOCKS) ? bsum[t] : 0;
    tmp[t] = v;
    __syncthreads();
#pragma unroll
    for (int off = 1; off < 256; off <<= 1) {
        int add = (t >= off) ? tmp[t - off] : 0;
        __syncthreads();
        tmp[t] += add;
        __syncthreads();
    }
    if (t < SCAN_BLOCKS) bbase[t] = tmp[t] - v;   // exclusive
}

__global__ __launch_bounds__(256) void scan3(const int* __restrict__ cnt,
                                             const int* __restrict__ bbase,
                                             int* __restrict__ off,
                                             int* __restrict__ cursor)
{
    __shared__ int tmp[256];
    int t = threadIdx.x;
    int i = blockIdx.x * 256 + t;
    int v = (i < NLIT) ? cnt[i] : 0;
    tmp[t] = v;
    __syncthreads();
#pragma unroll
    for (int offs = 1; offs < 256; offs <<= 1) {
        int add = (t >= offs) ? tmp[t - offs] : 0;
        __syncthreads();
        tmp[t] += add;
        __syncthreads();
    }
    if (i < NLIT) {
        int ex = bbase[blockIdx.x] + tmp[t] - v;
        off[i] = ex; cursor[i] = ex;
    }
    if (i == NLIT - 1) off[NLIT] = EDGES;
}

__global__ __launch_bounds__(256) void csr_scatter(const int* __restrict__ lit_idx,
                                                   int* __restrict__ cursor,
                                                   int* __restrict__ eidx)
{
    int e = blockIdx.x * 256 + threadIdx.x;
    if (e >= EDGES) return;
    int pos = atomicAdd(&cursor[lit_idx[e]], 1);
    eidx[pos] = e;
}

// -------- gather-based aggregation: agg[lit] = sum of h_c2l over CSR edges --------
__global__ __launch_bounds__(256) void aggregate(const unsigned short* __restrict__ h_c2l,
                                                 const int* __restrict__ off,
                                                 const int* __restrict__ eidx,
                                                 float* __restrict__ agg)
{
    int t = threadIdx.x;
    int lane8 = t & 7;
    int lit = blockIdx.x * 32 + (t >> 3);
    if (lit >= NLIT) return;
    int lo = off[lit], hi = off[lit + 1];
    float s[8] = {0, 0, 0, 0, 0, 0, 0, 0};
    for (int i = lo; i < hi; ++i) {
        int e = eidx[i];
        u16x8 hv = *(const u16x8*)(h_c2l + e * 64 + lane8 * 8);
#pragma unroll
        for (int j = 0; j < 8; ++j) s[j] += bf2f(hv[j]);
    }
    f32x4 a0, a1;
    a0[0] = s[0]; a0[1] = s[1]; a0[2] = s[2]; a0[3] = s[3];
    a1[0] = s[4]; a1[1] = s[5]; a1[2] = s[6]; a1[3] = s[7];
    *(f32x4*)(agg + lit * 64 + lane8 * 8)     = a0;
    *(f32x4*)(agg + lit * 64 + lane8 * 8 + 4) = a1;
}

// -------- init: h = feat @ W_init + b  (bf16) --------
__global__ __launch_bounds__(256) void init_kernel(
    const float* __restrict__ feat_l2c, const float* __restrict__ feat_c2l,
    const float* __restrict__ W_l2c, const float* __restrict__ b_l2c,
    const float* __restrict__ W_c2l, const float* __restrict__ b_c2l,
    unsigned short* __restrict__ h_l2c, unsigned short* __restrict__ h_c2l)
{
    int gid = blockIdx.x * 256 + threadIdx.x;
    if (gid >= EDGES * 8) return;
    int e = gid >> 3, fo = (gid & 7) << 3;
    float2 fl = *(const float2*)(feat_l2c + e * 2);
    float2 fc = *(const float2*)(feat_c2l + e * 2);

    u16x8 outl, outc;
#pragma unroll
    for (int j = 0; j < 8; ++j) {
        float wl0 = W_l2c[fo + j], wl1 = W_l2c[64 + fo + j];
        float wc0 = W_c2l[fo + j], wc1 = W_c2l[64 + fo + j];
        float vl = fl.x * wl0 + fl.y * wl1 + b_l2c[fo + j];
        float vc = fc.x * wc0 + fc.y * wc1 + b_c2l[fo + j];
        outl[j] = f2bf(vl);
        outc[j] = f2bf(vc);
    }
    *(u16x8*)(h_l2c + e * 64 + fo) = outl;
    *(u16x8*)(h_c2l + e * 64 + fo) = outc;
}

// -------- literal update: x0=(agg[lit]-h_c2l)/8 -> MLP3 -> merge(., h_l2c) -> h_l2c --------
__global__ __launch_bounds__(384) void lit_update(
    const unsigned short* __restrict__ h_c2l,
    unsigned short* __restrict__ h_l2c,
    const float* __restrict__ agg,
    const int* __restrict__ lit_idx,
    const unsigned short* __restrict__ wT,
    const float* __restrict__ msgl_b,
    const float* __restrict__ merge_b0,
    const float* __restrict__ merge_br)
{
    __shared__ __align__(16) char lds[LIT_WBYTES + WAVES_PB * 4096];   // 80 KiB
    int tid = threadIdx.x;
    stage_weights(wT, lds, LIT_WBYTES / 16, tid, 384);
    __syncthreads();

    int wv = tid >> 6, lane = tid & 63;
    int e16 = lane & 15, q = lane >> 4;
    int base = blockIdx.x * EPB + wv * 32;
    if (base >= EDGES) return;
    char* ldsw = lds + LIT_WBYTES + wv * 4096;
    int e_g[2] = { base + e16, base + 16 + e16 };
    int litn[2] = { lit_idx[e_g[0]], lit_idx[e_g[1]] };

    // prefetch old h_l2c fragments early (latency hides under msgl layers)
    s16x8 hfrag[2][2];
#pragma unroll
    for (int rb = 0; rb < 2; ++rb)
#pragma unroll
        for (int kk = 0; kk < 2; ++kk)
            hfrag[rb][kk] = *(const s16x8*)(h_l2c + e_g[rb] * 64 + kk * 32 + q * 8);

    s16x8 bfrag[2][2];
#pragma unroll
    for (int rb = 0; rb < 2; ++rb) {
        int eg = e_g[rb], lit = litn[rb];
#pragma unroll
        for (int kk = 0; kk < 2; ++kk) {
            int f0 = kk * 32 + q * 8;
            const float* ap = agg + lit * 64 + f0;
            f32x4 a0 = *(const f32x4*)ap;
            f32x4 a1 = *(const f32x4*)(ap + 4);
            u16x8 hv = *(const u16x8*)(h_c2l + eg * 64 + f0);
            s16x8 b;
#pragma unroll
            for (int j = 0; j < 4; ++j) b[j]     = (short)f2bf((a0[j] - bf2f(hv[j]))     * 0.125f);
#pragma unroll
            for (int j = 0; j < 4; ++j) b[4 + j] = (short)f2bf((a1[j] - bf2f(hv[4 + j])) * 0.125f);
            bfrag[rb][kk] = b;
        }
    }

    f32x4 acc[2][4];
    layer64_lds(lds,            msgl_b,       bfrag, acc, e16, q);
    relayout<true >(acc, bfrag, ldsw, e16, q);
    layer64_lds(lds + 8192,     msgl_b + 64,  bfrag, acc, e16, q);
    relayout<true >(acc, bfrag, ldsw, e16, q);
    layer64_lds(lds + 2 * 8192, msgl_b + 128, bfrag, acc, e16, q);
    relayout<false>(acc, bfrag, ldsw, e16, q);        // m fragments

    // merge layer 0: K=128, [m | h_l2c] ; units 3 (m part) and 4 (h part)
#pragma unroll
    for (int t = 0; t < 4; ++t) {
        f32x4 bv = *(const f32x4*)(merge_b0 + 16 * t + 4 * q);
        acc[0][t] = bv; acc[1][t] = bv;
    }
#pragma unroll
    for (int t = 0; t < 4; ++t) {
        int row = 16 * t + e16;
#pragma unroll
        for (int kk = 0; kk < 4; ++kk) {
            const char* ub = lds + (3 + (kk >> 1)) * 8192;
            s16x8 a = *(const s16x8*)(ub + row * 128 +
                                      (((kk & 1) * 64 + q * 16) ^ ((row & 7) << 4)));
            s16x8 b0 = (kk < 2) ? bfrag[0][kk] : hfrag[0][kk - 2];
            s16x8 b1 = (kk < 2) ? bfrag[1][kk] : hfrag[1][kk - 2];
            acc[0][t] = mfma16(a, b0, acc[0][t]);
            acc[1][t] = mfma16(a, b1, acc[1][t]);
        }
    }
    relayout<true>(acc, bfrag, ldsw, e16, q);
    layer64_lds(lds + 5 * 8192, merge_br,      bfrag, acc, e16, q);
    relayout<true>(acc, bfrag, ldsw, e16, q);
    layer64_lds(lds + 6 * 8192, merge_br + 64, bfrag, acc, e16, q);

    // store new h_l2c (bf16)
#pragma unroll
    for (int rb = 0; rb < 2; ++rb) {
        int eg = e_g[rb];
#pragma unroll
        for (int t = 0; t < 4; ++t) {
            f32x4 v = acc[rb][t];
            u16x4 p;
            p[0] = f2bf(v[0]); p[1] = f2bf(v[1]); p[2] = f2bf(v[2]); p[3] = f2bf(v[3]);
            *(u16x4*)(h_l2c + eg * 64 + 16 * t + 4 * q) = p;
        }
    }
}

// -------- clause update: x0=(sum of 2 siblings)/8 -> MLP3 -> h_c2l --------
__global__ __launch_bounds__(384) void clause_update(
    const unsigned short* __restrict__ h_l2c,
    unsigned short* __restrict__ h_c2l,
    const unsigned short* __restrict__ msgcT,
    const float* __restrict__ msgc_b)
{
    __shared__ __align__(16) char lds[CLS_WBYTES + WAVES_PB * 4096];   // 48 KiB
    int tid = threadIdx.x;
    stage_weights(msgcT, lds, CLS_WBYTES / 16, tid, 384);
    __syncthreads();

    int wv = tid >> 6, lane = tid & 63;
    int e16 = lane & 15, q = lane >> 4;
    int base = blockIdx.x * EPB + wv * 32;
    if (base >= EDGES) return;
    char* ldsw = lds + CLS_WBYTES + wv * 4096;
    int e_g[2] = { base + e16, base + 16 + e16 };

    s16x8 bfrag[2][2];
#pragma unroll
    for (int rb = 0; rb < 2; ++rb) {
        int eg = e_g[rb];
        int c3 = (eg / 3) * 3;
        int d = eg - c3;
        int e1 = c3 + (d == 0 ? 1 : 0);
        int e2 = c3 + (d == 2 ? 1 : 2);
#pragma unroll
        for (int kk = 0; kk < 2; ++kk) {
            int f0 = kk * 32 + q * 8;
            u16x8 h1 = *(const u16x8*)(h_l2c + e1 * 64 + f0);
            u16x8 h2 = *(const u16x8*)(h_l2c + e2 * 64 + f0);
            s16x8 b;
#pragma unroll
            for (int j = 0; j < 8; ++j)
                b[j] = (short)f2bf((bf2f(h1[j]) + bf2f(h2[j])) * 0.125f);
            bfrag[rb][kk] = b;
        }
    }

    f32x4 acc[2][4];
    layer64_lds(lds,            msgc_b,       bfrag, acc, e16, q);
    relayout<true>(acc, bfrag, ldsw, e16, q);
    layer64_lds(lds + 8192,     msgc_b + 64,  bfrag, acc, e16, q);
    relayout<true>(acc, bfrag, ldsw, e16, q);
    layer64_lds(lds + 2 * 8192, msgc_b + 128, bfrag, acc, e16, q);

#pragma unroll
    for (int rb = 0; rb < 2; ++rb) {
        int eg = e_g[rb];
#pragma unroll
        for (int t = 0; t < 4; ++t) {
            f32x4 v = acc[rb][t];
            u16x4 p;
            p[0] = f2bf(v[0]); p[1] = f2bf(v[1]); p[2] = f2bf(v[2]); p[3] = f2bf(v[3]);
            *(u16x4*)(h_c2l + eg * 64 + 16 * t + 4 * q) = p;
        }
    }
}

// -------- readout stage 1: per-graph sum of h_c2l over contiguous 75000 edges --------
__global__ __launch_bounds__(256) void readout_sum(
    const unsigned short* __restrict__ h_c2l, float* __restrict__ ro_acc)
{
    __shared__ float lsum[32][64];
    int g = blockIdx.x >> 6, chunk = blockIdx.x & 63;
    int t = threadIdx.x;
    int fg = t & 7, el = t >> 3;
    float s[8] = {0, 0, 0, 0, 0, 0, 0, 0};
    for (int idx = chunk * 32 + el; idx < EPG; idx += 2048) {
        u16x8 hv = *(const u16x8*)(h_c2l + (g * EPG + idx) * 64 + fg * 8);
#pragma unroll
        for (int j = 0; j < 8; ++j) s[j] += bf2f(hv[j]);
    }
#pragma unroll
    for (int j = 0; j < 8; ++j) lsum[el][fg * 8 + j] = s[j];
    __syncthreads();
    if (t < 64) {
        float tot = 0.f;
#pragma unroll 8
        for (int r = 0; r < 32; ++r) tot += lsum[r][t];
        atomicAdd(&ro_acc[g * 64 + t], tot);
    }
}

// -------- readout stage 2: tiny MLP + sigmoid --------
__global__ __launch_bounds__(256) void readout_mlp(
    const float* __restrict__ ro_acc, const float* __restrict__ ro_W,
    const float* __restrict__ ro_b, const float* __restrict__ ro_W2,
    const float* __restrict__ ro_b2, float* __restrict__ out)
{
    __shared__ float xb[NGRAPH][HDIM];
    __shared__ float yb[NGRAPH][HDIM];
    int g = threadIdx.x >> 6;
    int j = threadIdx.x & 63;
    xb[g][j] = ro_acc[g * HDIM + j] * (1.0f / 12500.0f);
    __syncthreads();
    float a = ro_b[j];
#pragma unroll 8
    for (int k = 0; k < HDIM; ++k) a += xb[g][k] * ro_W[k * HDIM + j];
    a = fmaxf(a, 0.0f);
    yb[g][j] = a;
    __syncthreads();
    float a2 = ro_b[HDIM + j];
#pragma unroll 8
    for (int k = 0; k < HDIM; ++k) a2 += yb[g][k] * ro_W[4096 + k * HDIM + j];
    a2 = fmaxf(a2, 0.0f);
    float p = a2 * ro_W2[j];
#pragma unroll
    for (int off = 32; off > 0; off >>= 1) p += __shfl_down(p, off, 64);
    if (j == 0) out[g] = 1.0f / (1.0f + expf(-(p + ro_b2[0])));
}

extern "C" void kernel_launch(void* const* d_in, const int* in_sizes, int n_in,
                              void* d_out, int out_size, void* d_ws, size_t ws_size,
                              hipStream_t stream)
{
    const float* feat_l2c = (const float*)d_in[0];
    const float* feat_c2l = (const float*)d_in[1];
    const int*   lit_idx  = (const int*)d_in[2];
    // d_in[3] (cls_idx) unused: edges are clause-major by construction
    const float* W_l2c    = (const float*)d_in[4];
    const float* b_l2c    = (const float*)d_in[5];
    const float* W_c2l    = (const float*)d_in[6];
    const float* b_c2l    = (const float*)d_in[7];
    const float* msgl_W   = (const float*)d_in[8];
    const float* msgl_b   = (const float*)d_in[9];
    const float* merge_W0 = (const float*)d_in[10];
    const float* merge_b0 = (const float*)d_in[11];
    const float* merge_Wr = (const float*)d_in[12];
    const float* merge_br = (const float*)d_in[13];
    const float* msgc_W   = (const float*)d_in[14];
    const float* msgc_b   = (const float*)d_in[15];
    const float* ro_W     = (const float*)d_in[16];
    const float* ro_b     = (const float*)d_in[17];
    const float* ro_W2    = (const float*)d_in[18];
    const float* ro_b2    = (const float*)d_in[19];

    char* ws = (char*)d_ws;
    unsigned short* h_l2c  = (unsigned short*)(ws + OFF_HL2C);
    unsigned short* h_c2l  = (unsigned short*)(ws + OFF_HC2L);
    float*          agg    = (float*)(ws + OFF_AGG);
    unsigned short* wT     = (unsigned short*)(ws + OFF_WT);
    float*          ro_acc = (float*)(ws + OFF_ROACC);
    int*            cnt    = (int*)(ws + OFF_CNT);
    int*            csroff = (int*)(ws + OFF_CSROFF);
    int*            cursor = (int*)(ws + OFF_CURSOR);
    int*            eidx   = (int*)(ws + OFF_EIDX);
    int*            bsum   = (int*)(ws + OFF_BSUM);
    int*            bbase  = (int*)(ws + OFF_BBASE);

    hipMemsetAsync(cnt, 0, NLIT * sizeof(int), stream);
    hipMemsetAsync(ro_acc, 0, NGRAPH * 64 * sizeof(float), stream);

    prep_weights<<<(WT_TOTAL + 255) / 256, 256, 0, stream>>>(msgl_W, merge_W0, merge_Wr, msgc_W, wT);

    // CSR of lit_idx (per-launch rebuild; 3-stage parallel scan)
    csr_hist<<<(EDGES + 255) / 256, 256, 0, stream>>>(lit_idx, cnt);
    scan1<<<SCAN_BLOCKS, 256, 0, stream>>>(cnt, bsum);
    scan2<<<1, 256, 0, stream>>>(bsum, bbase);
    scan3<<<SCAN_BLOCKS, 256, 0, stream>>>(cnt, bbase, csroff, cursor);
    csr_scatter<<<(EDGES + 255) / 256, 256, 0, stream>>>(lit_idx, cursor, eidx);

    init_kernel<<<EDGES * 8 / 256, 256, 0, stream>>>(feat_l2c, feat_c2l, W_l2c, b_l2c,
                                                     W_c2l, b_c2l, h_l2c, h_c2l);
    for (int r = 0; r < 3; ++r) {
        aggregate<<<(NLIT + 31) / 32, 256, 0, stream>>>(h_c2l, csroff, eidx, agg);
        lit_update<<<GRID_EDGE, 384, 0, stream>>>(h_c2l, h_l2c, agg, lit_idx, wT,
                                                  msgl_b, merge_b0, merge_br);
        clause_update<<<GRID_EDGE, 384, 0, stream>>>(h_l2c, h_c2l, wT + WT_CLS_ELEM, msgc_b);
    }
    readout_sum<<<256, 256, 0, stream>>>(h_c2l, ro_acc);
    readout_mlp<<<1, 256, 0, stream>>>(ro_acc, ro_W, ro_b, ro_W2, ro_b2, (float*)d_out);
}

// Round 5
// 332.683 us; speedup vs baseline: 4.4428x; 1.3362x over previous
//
#include <hip/hip_runtime.h>
#include <stdint.h>

// ---------------- problem constants ----------------
#define EDGES   300000
#define NLIT    50000
#define NGRAPH  4
#define EPG     75000          // edges per graph (contiguous)
#define HDIM    64

// ws layout (bytes)
#define OFF_HL2C   0
#define OFF_HC2L   38400000
#define OFF_AGG    76800000
#define OFF_WT     89600000
#define OFF_ROACC  89681920
#define OFF_CNT    89682944
#define OFF_CSROFF 89882944
#define OFF_CURSOR 90082948
#define OFF_EIDX   90282948
#define OFF_BSUM   91482948
#define OFF_BBASE  91484000
// end ~91.5 MB

// wT global layout: 10 "units", each [64 rows=out][64 cols=in] bf16 (4096 elems),
// stored PRE-SWIZZLED: element (u,row,col) at u*4096 + row*64 + (col ^ ((row&7)<<3)).
// u0-2: msglT ; u3: merge0T cols 0-63 (m part) ; u4: merge0T cols 64-127 (h part)
// u5-6: mergeRT ; u7-9: msgcT
#define WT_TOTAL    40960
#define WT_CLS_ELEM 28672      // element offset of clause units (u7)

#define LIT_WBYTES (7 * 8192)   // 57344
#define CLS_WBYTES (3 * 8192)   // 24576
#define EPB2       256          // edges per block (8 waves x 32)
#define GRID_EDGE  ((EDGES + EPB2 - 1) / EPB2)   // 1172

#define SCAN_BLOCKS ((NLIT + 255) / 256)   // 196

typedef __attribute__((ext_vector_type(8)))  short          s16x8;
typedef __attribute__((ext_vector_type(8)))  unsigned short u16x8;
typedef __attribute__((ext_vector_type(4)))  unsigned short u16x4;
typedef __attribute__((ext_vector_type(4)))  float          f32x4;
typedef __attribute__((ext_vector_type(16))) float          f32x16;

__device__ __forceinline__ f32x16 mfma32(s16x8 a, s16x8 b, f32x16 c) {
    return __builtin_amdgcn_mfma_f32_32x32x16_bf16(a, b, c, 0, 0, 0);
}
__device__ __forceinline__ float bf2f(unsigned short s) {
    union { unsigned int u; float f; } v; v.u = ((unsigned int)s) << 16; return v.f;
}
__device__ __forceinline__ unsigned short f2bf(float f) {
    union { float f; unsigned int u; } v; v.f = f;
    return (unsigned short)((v.u + 0x7fffu + ((v.u >> 16) & 1u)) >> 16);
}
__device__ __forceinline__ unsigned pk2(float a, float b) {
    return (unsigned)f2bf(a) | ((unsigned)f2bf(b) << 16);
}

// one 64->64 layer, 32x32x16 MFMA, weights in swizzled LDS unit, bias in LDS
__device__ __forceinline__ void layer32(const char* __restrict__ unitBase,
                                        const float* __restrict__ biasL,
                                        const s16x8 (&bin)[4], f32x16 (&acc)[2],
                                        int eL, int hi)
{
#pragma unroll
    for (int t = 0; t < 2; ++t)
#pragma unroll
        for (int g = 0; g < 4; ++g) {
            f32x4 bv = *(const f32x4*)(biasL + 32 * t + 8 * g + 4 * hi);
#pragma unroll
            for (int r = 0; r < 4; ++r) acc[t][4 * g + r] = bv[r];
        }
#pragma unroll
    for (int kb = 0; kb < 4; ++kb)
#pragma unroll
        for (int t = 0; t < 2; ++t) {
            int row = 32 * t + eL;
            s16x8 a = *(const s16x8*)(unitBase + row * 128 +
                                      ((32 * kb + 16 * hi) ^ ((row & 7) << 4)));
            acc[t] = mfma32(a, bin[kb], acc[t]);
        }
}

// in-register C->B relayout: per kb, slots come from own regs + lane^32 partner
template<bool RELU>
__device__ __forceinline__ void relayout32(f32x16 (&acc)[2], s16x8 (&bout)[4],
                                           int bpidx, int hi)
{
    if (RELU) {
#pragma unroll
        for (int t = 0; t < 2; ++t)
#pragma unroll
            for (int i = 0; i < 16; ++i) acc[t][i] = fmaxf(acc[t][i], 0.f);
    }
#pragma unroll
    for (int kb = 0; kb < 4; ++kb) {
        int m0 = 2 * kb, m1 = 2 * kb + 1;
        int t0 = m0 >> 2, g0 = m0 & 3, t1 = m1 >> 2, g1 = m1 & 3;
        unsigned A0 = pk2(acc[t0][4 * g0 + 0], acc[t0][4 * g0 + 1]);
        unsigned A1 = pk2(acc[t0][4 * g0 + 2], acc[t0][4 * g0 + 3]);
        unsigned B0 = pk2(acc[t1][4 * g1 + 0], acc[t1][4 * g1 + 1]);
        unsigned B1 = pk2(acc[t1][4 * g1 + 2], acc[t1][4 * g1 + 3]);
        unsigned pA0 = (unsigned)__builtin_amdgcn_ds_bpermute(bpidx, (int)A0);
        unsigned pA1 = (unsigned)__builtin_amdgcn_ds_bpermute(bpidx, (int)A1);
        unsigned pB0 = (unsigned)__builtin_amdgcn_ds_bpermute(bpidx, (int)B0);
        unsigned pB1 = (unsigned)__builtin_amdgcn_ds_bpermute(bpidx, (int)B1);
        union { unsigned w[4]; s16x8 v; } u;
        u.w[0] = hi ? pB0 : A0;
        u.w[1] = hi ? pB1 : A1;
        u.w[2] = hi ? B0 : pA0;
        u.w[3] = hi ? B1 : pA1;
        bout[kb] = u.v;
    }
}

__device__ __forceinline__ void store32(const f32x16 (&acc)[2],
                                        unsigned short* __restrict__ dst, int hi)
{
#pragma unroll
    for (int t = 0; t < 2; ++t)
#pragma unroll
        for (int g = 0; g < 4; ++g) {
            u16x4 p;
#pragma unroll
            for (int r = 0; r < 4; ++r) p[r] = f2bf(acc[t][4 * g + r]);
            *(u16x4*)(dst + 32 * t + 8 * g + 4 * hi) = p;
        }
}

// -------- transpose + bf16 + PRE-SWIZZLE all round weights into unit layout --------
__global__ __launch_bounds__(256) void prep_weights(
    const float* __restrict__ msgl_W, const float* __restrict__ merge_W0,
    const float* __restrict__ merge_Wr, const float* __restrict__ msgc_W,
    unsigned short* __restrict__ wT)
{
    int gid = blockIdx.x * 256 + threadIdx.x;
    if (gid >= WT_TOTAL) return;
    int unit = gid >> 12;
    int o = (gid >> 6) & 63;              // row = out
    int csw = gid & 63;
    int i = csw ^ ((o & 7) << 3);         // col = in (un-swizzled)
    float v;
    if (unit < 3)       v = msgl_W[unit * 4096 + i * 64 + o];
    else if (unit < 5)  v = merge_W0[((unit - 3) * 64 + i) * 64 + o];
    else if (unit < 7)  v = merge_Wr[(unit - 5) * 4096 + i * 64 + o];
    else                v = msgc_W[(unit - 7) * 4096 + i * 64 + o];
    wT[gid] = f2bf(v);
}

// -------- CSR build: histogram -> 3-stage parallel scan -> scatter --------
__global__ __launch_bounds__(256) void csr_hist(const int* __restrict__ lit_idx,
                                                int* __restrict__ cnt)
{
    int e = blockIdx.x * 256 + threadIdx.x;
    if (e < EDGES) atomicAdd(&cnt[lit_idx[e]], 1);
}

__global__ __launch_bounds__(256) void scan1(const int* __restrict__ cnt,
                                             int* __restrict__ bsum)
{
    __shared__ int red[4];
    int i = blockIdx.x * 256 + threadIdx.x;
    int s = (i < NLIT) ? cnt[i] : 0;
#pragma unroll
    for (int off = 1; off < 64; off <<= 1) s += __shfl_xor(s, off, 64);
    if ((threadIdx.x & 63) == 0) red[threadIdx.x >> 6] = s;
    __syncthreads();
    if (threadIdx.x == 0) bsum[blockIdx.x] = red[0] + red[1] + red[2] + red[3];
}

__global__ __launch_bounds__(256) void scan2(const int* __restrict__ bsum,
                                             int* __restrict__ bbase)
{
    __shared__ int tmp[256];
    int t = threadIdx.x;
    int v = (t < SCAN_BLOCKS) ? bsum[t] : 0;
    tmp[t] = v;
    __syncthreads();
#pragma unroll
    for (int off = 1; off < 256; off <<= 1) {
        int add = (t >= off) ? tmp[t - off] : 0;
        __syncthreads();
        tmp[t] += add;
        __syncthreads();
    }
    if (t < SCAN_BLOCKS) bbase[t] = tmp[t] - v;   // exclusive
}

__global__ __launch_bounds__(256) void scan3(const int* __restrict__ cnt,
                                             const int* __restrict__ bbase,
                                             int* __restrict__ off,
                                             int* __restrict__ cursor)
{
    __shared__ int tmp[256];
    int t = threadIdx.x;
    int i = blockIdx.x * 256 + t;
    int v = (i < NLIT) ? cnt[i] : 0;
    tmp[t] = v;
    __syncthreads();
#pragma unroll
    for (int offs = 1; offs < 256; offs <<= 1) {
        int add = (t >= offs) ? tmp[t - offs] : 0;
        __syncthreads();
        tmp[t] += add;
        __syncthreads();
    }
    if (i < NLIT) {
        int ex = bbase[blockIdx.x] + tmp[t] - v;
        off[i] = ex; cursor[i] = ex;
    }
    if (i == NLIT - 1) off[NLIT] = EDGES;
}

__global__ __launch_bounds__(256) void csr_scatter(const int* __restrict__ lit_idx,
                                                   int* __restrict__ cursor,
                                                   int* __restrict__ eidx)
{
    int e = blockIdx.x * 256 + threadIdx.x;
    if (e >= EDGES) return;
    int pos = atomicAdd(&cursor[lit_idx[e]], 1);
    eidx[pos] = e;
}

// -------- gather-based aggregation: agg[lit] = sum of h_c2l over CSR edges --------
__global__ __launch_bounds__(256) void aggregate(const unsigned short* __restrict__ h_c2l,
                                                 const int* __restrict__ off,
                                                 const int* __restrict__ eidx,
                                                 float* __restrict__ agg)
{
    int t = threadIdx.x;
    int lane8 = t & 7;
    int lit = blockIdx.x * 32 + (t >> 3);
    if (lit >= NLIT) return;
    int lo = off[lit], hi = off[lit + 1];
    float s[8] = {0, 0, 0, 0, 0, 0, 0, 0};
    for (int i = lo; i < hi; ++i) {
        int e = eidx[i];
        u16x8 hv = *(const u16x8*)(h_c2l + e * 64 + lane8 * 8);
#pragma unroll
        for (int j = 0; j < 8; ++j) s[j] += bf2f(hv[j]);
    }
    f32x4 a0, a1;
    a0[0] = s[0]; a0[1] = s[1]; a0[2] = s[2]; a0[3] = s[3];
    a1[0] = s[4]; a1[1] = s[5]; a1[2] = s[6]; a1[3] = s[7];
    *(f32x4*)(agg + lit * 64 + lane8 * 8)     = a0;
    *(f32x4*)(agg + lit * 64 + lane8 * 8 + 4) = a1;
}

// -------- init: h = feat @ W_init + b  (bf16) --------
__global__ __launch_bounds__(256) void init_kernel(
    const float* __restrict__ feat_l2c, const float* __restrict__ feat_c2l,
    const float* __restrict__ W_l2c, const float* __restrict__ b_l2c,
    const float* __restrict__ W_c2l, const float* __restrict__ b_c2l,
    unsigned short* __restrict__ h_l2c, unsigned short* __restrict__ h_c2l)
{
    int gid = blockIdx.x * 256 + threadIdx.x;
    if (gid >= EDGES * 8) return;
    int e = gid >> 3, fo = (gid & 7) << 3;
    float2 fl = *(const float2*)(feat_l2c + e * 2);
    float2 fc = *(const float2*)(feat_c2l + e * 2);

    u16x8 outl, outc;
#pragma unroll
    for (int j = 0; j < 8; ++j) {
        float wl0 = W_l2c[fo + j], wl1 = W_l2c[64 + fo + j];
        float wc0 = W_c2l[fo + j], wc1 = W_c2l[64 + fo + j];
        float vl = fl.x * wl0 + fl.y * wl1 + b_l2c[fo + j];
        float vc = fc.x * wc0 + fc.y * wc1 + b_c2l[fo + j];
        outl[j] = f2bf(vl);
        outc[j] = f2bf(vc);
    }
    *(u16x8*)(h_l2c + e * 64 + fo) = outl;
    *(u16x8*)(h_c2l + e * 64 + fo) = outc;
}

// -------- literal update: x0=(agg[lit]-h_c2l)/8 -> MLP3 -> merge(., h_l2c) -> h_l2c --------
__global__ __launch_bounds__(512, 4) void lit_update(
    const unsigned short* __restrict__ h_c2l,
    unsigned short* __restrict__ h_l2c,
    const float* __restrict__ agg,
    const int* __restrict__ lit_idx,
    const unsigned short* __restrict__ wT,
    const float* __restrict__ msgl_b,
    const float* __restrict__ merge_b0,
    const float* __restrict__ merge_br)
{
    __shared__ __align__(16) char lds[LIT_WBYTES + 384 * 4];   // 58880 B -> 2 blocks/CU
    int tid = threadIdx.x;
#pragma unroll
    for (int c = 0; c < 7; ++c) {
        int idx = c * 512 + tid;
        *(u16x8*)(lds + idx * 16) = *(const u16x8*)(wT + idx * 8);
    }
    float* ldsBias = (float*)(lds + LIT_WBYTES);
    if (tid < 384) {
        float v;
        if (tid < 192)      v = msgl_b[tid];
        else if (tid < 256) v = merge_b0[tid - 192];
        else                v = merge_br[tid - 256];
        ldsBias[tid] = v;
    }
    __syncthreads();

    int wv = tid >> 6, lane = tid & 63;
    int base = blockIdx.x * EPB2 + wv * 32;
    if (base >= EDGES) return;
    int eL = lane & 31, hi = lane >> 5;
    int bpidx = (lane ^ 32) << 2;
    int e = base + eL;
    int lit = lit_idx[e];

    // old h_l2c fragments (merge kb 4-7) -- load early, hide under msgl layers
    s16x8 hfrag[4];
#pragma unroll
    for (int c = 0; c < 4; ++c)
        hfrag[c] = *(const s16x8*)(h_l2c + e * 64 + 16 * c + 8 * hi);

    // input x0 fragments
    s16x8 binp[4];
#pragma unroll
    for (int c = 0; c < 4; ++c) {
        int f0 = 16 * c + 8 * hi;
        f32x4 a0 = *(const f32x4*)(agg + lit * 64 + f0);
        f32x4 a1 = *(const f32x4*)(agg + lit * 64 + f0 + 4);
        u16x8 hv = *(const u16x8*)(h_c2l + e * 64 + f0);
        s16x8 b;
#pragma unroll
        for (int j = 0; j < 4; ++j) b[j]     = (short)f2bf((a0[j] - bf2f(hv[j]))     * 0.125f);
#pragma unroll
        for (int j = 0; j < 4; ++j) b[4 + j] = (short)f2bf((a1[j] - bf2f(hv[4 + j])) * 0.125f);
        binp[c] = b;
    }

    f32x16 acc[2];
    s16x8 bf[4];
    layer32(lds,            ldsBias,       binp, acc, eL, hi);
    relayout32<true >(acc, bf, bpidx, hi);
    layer32(lds + 8192,     ldsBias + 64,  bf, acc, eL, hi);
    relayout32<true >(acc, bf, bpidx, hi);
    layer32(lds + 2 * 8192, ldsBias + 128, bf, acc, eL, hi);
    relayout32<false>(acc, bf, bpidx, hi);        // m fragments

    // merge layer 0: K=128 = [m | h_old], units 3 (m) and 4 (h)
#pragma unroll
    for (int t = 0; t < 2; ++t)
#pragma unroll
        for (int g = 0; g < 4; ++g) {
            f32x4 bv = *(const f32x4*)(ldsBias + 192 + 32 * t + 8 * g + 4 * hi);
#pragma unroll
            for (int r = 0; r < 4; ++r) acc[t][4 * g + r] = bv[r];
        }
#pragma unroll
    for (int kb = 0; kb < 8; ++kb) {
        const char* ub = lds + (3 + (kb >> 2)) * 8192;
        s16x8 bop = (kb < 4) ? bf[kb] : hfrag[kb - 4];
#pragma unroll
        for (int t = 0; t < 2; ++t) {
            int row = 32 * t + eL;
            s16x8 a = *(const s16x8*)(ub + row * 128 +
                                      ((32 * (kb & 3) + 16 * hi) ^ ((row & 7) << 4)));
            acc[t] = mfma32(a, bop, acc[t]);
        }
    }
    relayout32<true>(acc, bf, bpidx, hi);
    layer32(lds + 5 * 8192, ldsBias + 256, bf, acc, eL, hi);
    relayout32<true>(acc, bf, bpidx, hi);
    layer32(lds + 6 * 8192, ldsBias + 320, bf, acc, eL, hi);

    store32(acc, h_l2c + e * 64, hi);
}

// -------- clause update: x0=(sum of 2 siblings)/8 -> MLP3 -> h_c2l --------
__global__ __launch_bounds__(512, 4) void clause_update(
    const unsigned short* __restrict__ h_l2c,
    unsigned short* __restrict__ h_c2l,
    const unsigned short* __restrict__ msgcT,
    const float* __restrict__ msgc_b)
{
    __shared__ __align__(16) char lds[CLS_WBYTES + 192 * 4];   // 25344 B
    int tid = threadIdx.x;
#pragma unroll
    for (int c = 0; c < 3; ++c) {
        int idx = c * 512 + tid;
        *(u16x8*)(lds + idx * 16) = *(const u16x8*)(msgcT + idx * 8);
    }
    float* ldsBias = (float*)(lds + CLS_WBYTES);
    if (tid < 192) ldsBias[tid] = msgc_b[tid];
    __syncthreads();

    int wv = tid >> 6, lane = tid & 63;
    int base = blockIdx.x * EPB2 + wv * 32;
    if (base >= EDGES) return;
    int eL = lane & 31, hi = lane >> 5;
    int bpidx = (lane ^ 32) << 2;
    int e = base + eL;

    int c3 = (e / 3) * 3;
    int d = e - c3;
    int e1 = c3 + (d == 0 ? 1 : 0);
    int e2 = c3 + (d == 2 ? 1 : 2);

    s16x8 binp[4];
#pragma unroll
    for (int c = 0; c < 4; ++c) {
        int f0 = 16 * c + 8 * hi;
        u16x8 h1 = *(const u16x8*)(h_l2c + e1 * 64 + f0);
        u16x8 h2 = *(const u16x8*)(h_l2c + e2 * 64 + f0);
        s16x8 b;
#pragma unroll
        for (int j = 0; j < 8; ++j)
            b[j] = (short)f2bf((bf2f(h1[j]) + bf2f(h2[j])) * 0.125f);
        binp[c] = b;
    }

    f32x16 acc[2];
    s16x8 bf[4];
    layer32(lds,            ldsBias,       binp, acc, eL, hi);
    relayout32<true>(acc, bf, bpidx, hi);
    layer32(lds + 8192,     ldsBias + 64,  bf, acc, eL, hi);
    relayout32<true>(acc, bf, bpidx, hi);
    layer32(lds + 2 * 8192, ldsBias + 128, bf, acc, eL, hi);

    store32(acc, h_c2l + e * 64, hi);
}

// -------- readout stage 1: per-graph sum of h_c2l over contiguous 75000 edges --------
__global__ __launch_bounds__(256) void readout_sum(
    const unsigned short* __restrict__ h_c2l, float* __restrict__ ro_acc)
{
    __shared__ float lsum[32][64];
    int g = blockIdx.x >> 6, chunk = blockIdx.x & 63;
    int t = threadIdx.x;
    int fg = t & 7, el = t >> 3;
    float s[8] = {0, 0, 0, 0, 0, 0, 0, 0};
    for (int idx = chunk * 32 + el; idx < EPG; idx += 2048) {
        u16x8 hv = *(const u16x8*)(h_c2l + (g * EPG + idx) * 64 + fg * 8);
#pragma unroll
        for (int j = 0; j < 8; ++j) s[j] += bf2f(hv[j]);
    }
#pragma unroll
    for (int j = 0; j < 8; ++j) lsum[el][fg * 8 + j] = s[j];
    __syncthreads();
    if (t < 64) {
        float tot = 0.f;
#pragma unroll 8
        for (int r = 0; r < 32; ++r) tot += lsum[r][t];
        atomicAdd(&ro_acc[g * 64 + t], tot);
    }
}

// -------- readout stage 2: tiny MLP + sigmoid --------
__global__ __launch_bounds__(256) void readout_mlp(
    const float* __restrict__ ro_acc, const float* __restrict__ ro_W,
    const float* __restrict__ ro_b, const float* __restrict__ ro_W2,
    const float* __restrict__ ro_b2, float* __restrict__ out)
{
    __shared__ float xb[NGRAPH][HDIM];
    __shared__ float yb[NGRAPH][HDIM];
    int g = threadIdx.x >> 6;
    int j = threadIdx.x & 63;
    xb[g][j] = ro_acc[g * HDIM + j] * (1.0f / 12500.0f);
    __syncthreads();
    float a = ro_b[j];
#pragma unroll 8
    for (int k = 0; k < HDIM; ++k) a += xb[g][k] * ro_W[k * HDIM + j];
    a = fmaxf(a, 0.0f);
    yb[g][j] = a;
    __syncthreads();
    float a2 = ro_b[HDIM + j];
#pragma unroll 8
    for (int k = 0; k < HDIM; ++k) a2 += yb[g][k] * ro_W[4096 + k * HDIM + j];
    a2 = fmaxf(a2, 0.0f);
    float p = a2 * ro_W2[j];
#pragma unroll
    for (int off = 32; off > 0; off >>= 1) p += __shfl_down(p, off, 64);
    if (j == 0) out[g] = 1.0f / (1.0f + expf(-(p + ro_b2[0])));
}

extern "C" void kernel_launch(void* const* d_in, const int* in_sizes, int n_in,
                              void* d_out, int out_size, void* d_ws, size_t ws_size,
                              hipStream_t stream)
{
    const float* feat_l2c = (const float*)d_in[0];
    const float* feat_c2l = (const float*)d_in[1];
    const int*   lit_idx  = (const int*)d_in[2];
    // d_in[3] (cls_idx) unused: edges are clause-major by construction
    const float* W_l2c    = (const float*)d_in[4];
    const float* b_l2c    = (const float*)d_in[5];
    const float* W_c2l    = (const float*)d_in[6];
    const float* b_c2l    = (const float*)d_in[7];
    const float* msgl_W   = (const float*)d_in[8];
    const float* msgl_b   = (const float*)d_in[9];
    const float* merge_W0 = (const float*)d_in[10];
    const float* merge_b0 = (const float*)d_in[11];
    const float* merge_Wr = (const float*)d_in[12];
    const float* merge_br = (const float*)d_in[13];
    const float* msgc_W   = (const float*)d_in[14];
    const float* msgc_b   = (const float*)d_in[15];
    const float* ro_W     = (const float*)d_in[16];
    const float* ro_b     = (const float*)d_in[17];
    const float* ro_W2    = (const float*)d_in[18];
    const float* ro_b2    = (const float*)d_in[19];

    char* ws = (char*)d_ws;
    unsigned short* h_l2c  = (unsigned short*)(ws + OFF_HL2C);
    unsigned short* h_c2l  = (unsigned short*)(ws + OFF_HC2L);
    float*          agg    = (float*)(ws + OFF_AGG);
    unsigned short* wT     = (unsigned short*)(ws + OFF_WT);
    float*          ro_acc = (float*)(ws + OFF_ROACC);
    int*            cnt    = (int*)(ws + OFF_CNT);
    int*            csroff = (int*)(ws + OFF_CSROFF);
    int*            cursor = (int*)(ws + OFF_CURSOR);
    int*            eidx   = (int*)(ws + OFF_EIDX);
    int*            bsum   = (int*)(ws + OFF_BSUM);
    int*            bbase  = (int*)(ws + OFF_BBASE);

    hipMemsetAsync(cnt, 0, NLIT * sizeof(int), stream);
    hipMemsetAsync(ro_acc, 0, NGRAPH * 64 * sizeof(float), stream);

    prep_weights<<<(WT_TOTAL + 255) / 256, 256, 0, stream>>>(msgl_W, merge_W0, merge_Wr, msgc_W, wT);

    // CSR of lit_idx (per-launch rebuild; 3-stage parallel scan)
    csr_hist<<<(EDGES + 255) / 256, 256, 0, stream>>>(lit_idx, cnt);
    scan1<<<SCAN_BLOCKS, 256, 0, stream>>>(cnt, bsum);
    scan2<<<1, 256, 0, stream>>>(bsum, bbase);
    scan3<<<SCAN_BLOCKS, 256, 0, stream>>>(cnt, bbase, csroff, cursor);
    csr_scatter<<<(EDGES + 255) / 256, 256, 0, stream>>>(lit_idx, cursor, eidx);

    init_kernel<<<EDGES * 8 / 256, 256, 0, stream>>>(feat_l2c, feat_c2l, W_l2c, b_l2c,
                                                     W_c2l, b_c2l, h_l2c, h_c2l);
    for (int r = 0; r < 3; ++r) {
        aggregate<<<(NLIT + 31) / 32, 256, 0, stream>>>(h_c2l, csroff, eidx, agg);
        lit_update<<<GRID_EDGE, 512, 0, stream>>>(h_c2l, h_l2c, agg, lit_idx, wT,
                                                  msgl_b, merge_b0, merge_br);
        clause_update<<<GRID_EDGE, 512, 0, stream>>>(h_l2c, h_c2l, wT + WT_CLS_ELEM, msgc_b);
    }
    readout_sum<<<256, 256, 0, stream>>>(h_c2l, ro_acc);
    readout_mlp<<<1, 256, 0, stream>>>(ro_acc, ro_W, ro_b, ro_W2, ro_b2, (float*)d_out);
}